// Round 9
// baseline (316.978 us; speedup 1.0000x reference)
//
#include <hip/hip_runtime.h>

typedef __attribute__((ext_vector_type(8))) short short8;
typedef __attribute__((ext_vector_type(4))) float f32x4;
typedef unsigned short USHORT;

#define DNORM 0.35355339059327373f  // 64^-0.25
#define AS1(p) ((const __attribute__((address_space(1))) void*)(p))
#define AS3(p) ((__attribute__((address_space(3))) void*)(p))

// ---------- helpers ----------
__device__ __forceinline__ USHORT f2bf(float f) {
  union { float f; unsigned u; } v; v.f = f;
  unsigned r = v.u + 0x7fffu + ((v.u >> 16) & 1u);
  return (USHORT)(r >> 16);
}
__device__ __forceinline__ float bf2f(USHORT u) {
  union { unsigned u; float f; } v; v.u = ((unsigned)u) << 16;
  return v.f;
}
__device__ __forceinline__ unsigned fkey(float f) {
  union { float f; unsigned u; } v; v.f = f;
  return (v.u & 0x80000000u) ? ~v.u : (v.u | 0x80000000u);
}
__device__ __forceinline__ float keyf(unsigned k) {
  union { unsigned u; float f; } v;
  v.u = (k & 0x80000000u) ? (k ^ 0x80000000u) : ~k;
  return v.f;
}

// stage 16 fp32 -> hi/lo bf16 into swizzled LDS rows
__device__ __forceinline__ void stage_hl16(const float* __restrict__ src,
                                           USHORT* __restrict__ Ah, USHORT* __restrict__ Al,
                                           int r, int kc) {
  float b[16];
  *(float4*)&b[0] = *(const float4*)(src);
  *(float4*)&b[4] = *(const float4*)(src + 4);
  *(float4*)&b[8] = *(const float4*)(src + 8);
  *(float4*)&b[12] = *(const float4*)(src + 12);
  const int swz = (r & 7) << 3;
  unsigned H[8], L[8];
#pragma unroll
  for (int p = 0; p < 8; ++p) {
    USHORT h0 = f2bf(b[2 * p]), h1 = f2bf(b[2 * p + 1]);
    USHORT l0 = f2bf(b[2 * p] - bf2f(h0)), l1 = f2bf(b[2 * p + 1] - bf2f(h1));
    H[p] = (unsigned)h0 | ((unsigned)h1 << 16);
    L[p] = (unsigned)l0 | ((unsigned)l1 << 16);
  }
  *(uint4*)&Ah[r * 64 + (kc ^ swz)] = make_uint4(H[0], H[1], H[2], H[3]);
  *(uint4*)&Ah[r * 64 + ((kc + 8) ^ swz)] = make_uint4(H[4], H[5], H[6], H[7]);
  *(uint4*)&Al[r * 64 + (kc ^ swz)] = make_uint4(L[0], L[1], L[2], L[3]);
  *(uint4*)&Al[r * 64 + ((kc + 8) ^ swz)] = make_uint4(L[4], L[5], L[6], L[7]);
}

// stage 16 fp32 -> hi bf16 only
__device__ __forceinline__ void stage_h16(const float* __restrict__ src,
                                          USHORT* __restrict__ Ah, int r, int kc) {
  float b[16];
  *(float4*)&b[0] = *(const float4*)(src);
  *(float4*)&b[4] = *(const float4*)(src + 4);
  *(float4*)&b[8] = *(const float4*)(src + 8);
  *(float4*)&b[12] = *(const float4*)(src + 12);
  const int swz = (r & 7) << 3;
  unsigned H[8];
#pragma unroll
  for (int p = 0; p < 8; ++p)
    H[p] = (unsigned)f2bf(b[2 * p]) | ((unsigned)f2bf(b[2 * p + 1]) << 16);
  *(uint4*)&Ah[r * 64 + (kc ^ swz)] = make_uint4(H[0], H[1], H[2], H[3]);
  *(uint4*)&Ah[r * 64 + ((kc + 8) ^ swz)] = make_uint4(H[4], H[5], H[6], H[7]);
}

// ---------- dtype detect ----------
__global__ __launch_bounds__(256) void detect_kernel(const USHORT* __restrict__ w,
                                                     int* __restrict__ flag) {
  const int t = threadIdx.x;
  unsigned mx = 0;
#pragma unroll 8
  for (int c = 0; c < 64; ++c) {
    unsigned a = (unsigned)w[c * 256 + t] & 0x7FFFu;
    if (a > mx) mx = a;
  }
  if (mx > 0x4480u) atomicOr(flag, 1);
}

// ---------- x -> bf16; tail blocks convert proj ----------
__global__ __launch_bounds__(256) void cvt_x_kernel(const void* __restrict__ xin,
                                                    USHORT* __restrict__ xh,
                                                    const void* __restrict__ proj,
                                                    USHORT* __restrict__ projc,
                                                    const int* __restrict__ flag) {
  if (blockIdx.x >= 4096) {
    const int i = ((blockIdx.x - 4096) * 256 + threadIdx.x) * 4;
    if (*flag) {
      float4 v = *(const float4*)((const float*)proj + i);
      USHORT a = f2bf(v.x), b = f2bf(v.y), c = f2bf(v.z), d = f2bf(v.w);
      *(uint2*)(projc + i) = make_uint2((unsigned)a | ((unsigned)b << 16),
                                        (unsigned)c | ((unsigned)d << 16));
    } else {
      *(uint2*)(projc + i) = *(const uint2*)((const USHORT*)proj + i);
    }
    return;
  }
  const size_t i = ((size_t)blockIdx.x * 256 + threadIdx.x) * 8;
  if (*flag) {
    const float* xf = (const float*)xin;
    float4 a = *(const float4*)(xf + i);
    float4 b = *(const float4*)(xf + i + 4);
    float c[8] = {a.x, a.y, a.z, a.w, b.x, b.y, b.z, b.w};
    unsigned ho[4];
#pragma unroll
    for (int j = 0; j < 4; ++j) {
      USHORT h0 = f2bf(c[2 * j]), h1 = f2bf(c[2 * j + 1]);
      ho[j] = (unsigned)h0 | ((unsigned)h1 << 16);
    }
    *(uint4*)(xh + i) = make_uint4(ho[0], ho[1], ho[2], ho[3]);
  } else {
    uint4 u = *(const uint4*)((const USHORT*)xin + i);
    *(uint4*)(xh + i) = u;
  }
}

// ---------- sinu -> transposed fp32 tables ----------
__global__ __launch_bounds__(256) void sinut_kernel(const void* __restrict__ sinu,
                                                    float* __restrict__ sinuT,
                                                    const int* __restrict__ flag) {
  const int l = blockIdx.x * 256 + threadIdx.x;
  if (*flag) {
    const float* s = (const float*)sinu + (size_t)l * 64;
#pragma unroll 8
    for (int j2 = 0; j2 < 32; ++j2) {
      sinuT[j2 * 4096 + l] = s[j2];
      sinuT[131072 + j2 * 4096 + l] = s[32 + j2];
    }
  } else {
    const USHORT* s = (const USHORT*)sinu + (size_t)l * 64;
#pragma unroll 8
    for (int j2 = 0; j2 < 32; ++j2) {
      sinuT[j2 * 4096 + l] = bf2f(s[j2]);
      sinuT[131072 + j2 * 4096 + l] = bf2f(s[32 + j2]);
    }
  }
}

// ---------- transpose W ----------
__global__ __launch_bounds__(256) void transpose_w_kernel(const void* __restrict__ Wq,
                                                          const void* __restrict__ Wk,
                                                          const void* __restrict__ Wv,
                                                          const void* __restrict__ Wo,
                                                          USHORT* __restrict__ wqkvt,
                                                          USHORT* __restrict__ wot,
                                                          const int* __restrict__ flag) {
  __shared__ __align__(16) USHORT tile[64][80];
  const int z = blockIdx.z;
  const void* src = (z == 0) ? Wq : (z == 1) ? Wk : (z == 2) ? Wv : Wo;
  USHORT* dst = (z < 3) ? (wqkvt + (size_t)z * 1048576) : wot;
  const int r0 = blockIdx.y * 64, c0 = blockIdx.x * 64;
  const int t = threadIdx.x;
  const int rr = t >> 2, c4 = (t & 3) * 16;
  if (*flag) {
    const float* s = (const float*)src + (size_t)(r0 + rr) * 1024 + c0 + c4;
#pragma unroll
    for (int i = 0; i < 4; ++i) {
      float4 v = *(const float4*)(s + i * 4);
      tile[rr][c4 + i * 4 + 0] = f2bf(v.x);
      tile[rr][c4 + i * 4 + 1] = f2bf(v.y);
      tile[rr][c4 + i * 4 + 2] = f2bf(v.z);
      tile[rr][c4 + i * 4 + 3] = f2bf(v.w);
    }
  } else {
    const USHORT* s = (const USHORT*)src + (size_t)(r0 + rr) * 1024 + c0 + c4;
    *(uint4*)&tile[rr][c4] = *(const uint4*)s;
    *(uint4*)&tile[rr][c4 + 8] = *(const uint4*)(s + 8);
  }
  __syncthreads();
  USHORT tmp[16];
#pragma unroll
  for (int i = 0; i < 16; ++i) tmp[i] = tile[c4 + i][rr];
  uint4 o0, o1;
  o0.x = (unsigned)tmp[0] | ((unsigned)tmp[1] << 16);
  o0.y = (unsigned)tmp[2] | ((unsigned)tmp[3] << 16);
  o0.z = (unsigned)tmp[4] | ((unsigned)tmp[5] << 16);
  o0.w = (unsigned)tmp[6] | ((unsigned)tmp[7] << 16);
  o1.x = (unsigned)tmp[8] | ((unsigned)tmp[9] << 16);
  o1.y = (unsigned)tmp[10] | ((unsigned)tmp[11] << 16);
  o1.z = (unsigned)tmp[12] | ((unsigned)tmp[13] << 16);
  o1.w = (unsigned)tmp[14] | ((unsigned)tmp[15] << 16);
  USHORT* d = dst + (size_t)(c0 + rr) * 1024 + r0 + c4;
  *(uint4*)d = o0;
  *(uint4*)(d + 8) = o1;
}

// ---------- GEMM (m97 structure, global_load_lds + XOR swizzle, XCD swizzle) ----------
template <bool ROTEPI, bool FLAGOUT>
__global__ __launch_bounds__(256) void gemm_bt(const USHORT* __restrict__ A,
                                               const USHORT* __restrict__ Bt,
                                               void* __restrict__ Cv,
                                               USHORT* __restrict__ Vb,
                                               const float* __restrict__ sinuT,
                                               float* __restrict__ diag_q,
                                               float* __restrict__ diag_k,
                                               int M, int N, int K, int lda, int ldb, int ldc,
                                               int ldv, int NLO, const int* __restrict__ flag) {
  __shared__ __align__(16) USHORT As[8192];   // [128][64] swizzled
  __shared__ __align__(16) USHORT Bs[8192];   // [128][64] swizzled
  const int fl = *flag;
  const int t = threadIdx.x;
  const int lane = t & 63, wave = t >> 6;
  const int lr = lane & 15, lg = lane >> 4;
  const int nwg = gridDim.x * gridDim.y;
  const int orig = blockIdx.y * gridDim.x + blockIdx.x;
  const int tile = (orig & 7) * (nwg >> 3) + (orig >> 3);
  const int bx = tile % gridDim.x, by = tile / gridDim.x;
  const int row0 = by * 128, col0 = bx * 128;
  const int wr = (wave >> 1) * 64, wc = (wave & 1) * 64;
  // hoisted staging pointers (incremented by 64 each K-iter)
  const USHORT* pa[4];
  const USHORT* pb[4];
#pragma unroll
  for (int c = 0; c < 4; ++c) {
    const int e = c * 256 + t;
    const int r = e >> 3;
    const int ch = (t & 7) ^ (r & 7);
    pa[c] = A + (size_t)(row0 + r) * lda + ch * 8;
    pb[c] = Bt + (size_t)(col0 + r) * ldb + ch * 8;
  }
  f32x4 acc[4][4] = {};
  for (int k0 = 0; k0 < K; k0 += 64) {
#pragma unroll
    for (int c = 0; c < 4; ++c) {
      __builtin_amdgcn_global_load_lds(AS1(pa[c]), AS3(&As[c * 2048 + wave * 512]), 16, 0, 0);
      __builtin_amdgcn_global_load_lds(AS1(pb[c]), AS3(&Bs[c * 2048 + wave * 512]), 16, 0, 0);
      pa[c] += 64;
      pb[c] += 64;
    }
    __syncthreads();
#pragma unroll
    for (int ks = 0; ks < 2; ++ks) {
      const int koff = ks * 32 + (lg << 3);
      short8 av_[4], bv[4];
#pragma unroll
      for (int i = 0; i < 4; ++i) {
        const int ar = wr + i * 16 + lr;
        av_[i] = *(const short8*)&As[ar * 64 + (koff ^ ((ar & 7) << 3))];
      }
#pragma unroll
      for (int j = 0; j < 4; ++j) {
        const int br = wc + j * 16 + lr;
        bv[j] = *(const short8*)&Bs[br * 64 + (koff ^ ((br & 7) << 3))];
      }
#pragma unroll
      for (int i = 0; i < 4; ++i)
#pragma unroll
        for (int j = 0; j < 4; ++j)
          acc[i][j] = __builtin_amdgcn_mfma_f32_16x16x32_bf16(av_[i], bv[j], acc[i][j], 0, 0, 0);
    }
    __syncthreads();
  }
  if constexpr (ROTEPI) {
    if (col0 < NLO) {
      const int G0 = col0 + wc;
      const int which = G0 >> 10;
      const int h = (G0 & 1023) >> 6;
      const int par = lr & 1;
      float* qk = (float*)Cv;
#pragma unroll
      for (int i = 0; i < 4; ++i) {
        const int R0 = row0 + wr + i * 16 + (lg << 2);
        const int l0 = R0 & 4095;
        float ss[4] = {0.f, 0.f, 0.f, 0.f};
#pragma unroll
        for (int j = 0; j < 4; ++j) {
          const int j2 = j * 8 + (lr >> 1);
          const float4 s4 = *(const float4*)&sinuT[(size_t)j2 * 4096 + l0];
          const float4 c4 = *(const float4*)&sinuT[131072 + (size_t)j2 * 4096 + l0];
          const float sv[4] = {s4.x, s4.y, s4.z, s4.w};
          const float cw[4] = {c4.x, c4.y, c4.z, c4.w};
          const int G = G0 + j * 16 + lr;
#pragma unroll
          for (int r = 0; r < 4; ++r) {
            const float own = acc[i][j][r];
            const float oth = __shfl_xor(own, 1);
            const float ro = par ? (own * cw[r] + oth * sv[r]) : (own * cw[r] - oth * sv[r]);
            ss[r] += ro * ro;
            qk[(size_t)(R0 + r) * ldc + G] = ro;
          }
        }
#pragma unroll
        for (int r = 0; r < 4; ++r) {
          float v_ = ss[r];
          v_ += __shfl_xor(v_, 1);
          v_ += __shfl_xor(v_, 2);
          v_ += __shfl_xor(v_, 4);
          v_ += __shfl_xor(v_, 8);
          if (lr == 0)
            (which ? diag_k : diag_q)[(R0 + r) * 16 + h] = v_ * 0.0625f;
        }
      }
    } else {
#pragma unroll
      for (int i = 0; i < 4; ++i) {
#pragma unroll
        for (int r = 0; r < 4; ++r) {
          const int row = row0 + wr + i * 16 + (lg << 2) + r;
#pragma unroll
          for (int j = 0; j < 4; ++j) {
            const int col = col0 + wc + j * 16 + lr - NLO;
            Vb[(size_t)row * ldv + col] = f2bf(acc[i][j][r]);
          }
        }
      }
    }
    return;
  }
#pragma unroll
  for (int i = 0; i < 4; ++i) {
#pragma unroll
    for (int r = 0; r < 4; ++r) {
      const int row = row0 + wr + i * 16 + (lg << 2) + r;
#pragma unroll
      for (int j = 0; j < 4; ++j) {
        const int col = col0 + wc + j * 16 + lr;
        const float v = acc[i][j][r];
        if constexpr (FLAGOUT) {
          if (fl) ((float*)Cv)[(size_t)row * ldc + col] = v;
          else ((USHORT*)Cv)[(size_t)row * ldc + col] = f2bf(v);
        } else {
          ((USHORT*)Cv)[(size_t)row * ldc + col] = f2bf(v);
        }
      }
    }
  }
}

// ---------- ddk max (hi-only dd; proj B-frags direct from global) ----------
__global__ __launch_bounds__(256) void ddk_max_kernel(const float* __restrict__ qkf,
                                                      const USHORT* __restrict__ proj,
                                                      unsigned* __restrict__ mk) {
  __shared__ __align__(16) USHORT Ah[4096];
  const int t = threadIdx.x, lane = t & 63, wave = t >> 6;
  const int lr = lane & 15, lg = lane >> 4;
  const int bh = blockIdx.y, b = bh >> 4, h = bh & 15;
  const size_t grow0 = (size_t)b * 4096 + blockIdx.x * 64;
  {
    const int r = t >> 2, kc = (t & 3) * 16;
    stage_h16(qkf + (grow0 + r) * 2048 + 1024 + h * 64 + kc, Ah, r, kc);
  }
  __syncthreads();
  f32x4 acc[16] = {};
#pragma unroll
  for (int ks = 0; ks < 2; ++ks) {
    const int koff = ks * 32 + (lg << 3);
    const int ar = wave * 16 + lr;
    short8 a_h = *(const short8*)&Ah[ar * 64 + (koff ^ ((ar & 7) << 3))];
#pragma unroll
    for (int n = 0; n < 16; ++n) {
      short8 b_h = *(const short8*)&proj[(n * 16 + lr) * 64 + koff];
      acc[n] = __builtin_amdgcn_mfma_f32_16x16x32_bf16(a_h, b_h, acc[n], 0, 0, 0);
    }
  }
#pragma unroll
  for (int r = 0; r < 4; ++r) {
    float m_ = acc[0][r];
#pragma unroll
    for (int n = 1; n < 16; ++n) m_ = fmaxf(m_, acc[n][r]);
    m_ = fmaxf(m_, __shfl_xor(m_, 1));
    m_ = fmaxf(m_, __shfl_xor(m_, 2));
    m_ = fmaxf(m_, __shfl_xor(m_, 4));
    m_ = fmaxf(m_, __shfl_xor(m_, 8));
    if (lr == 0) {
      const int row = (int)grow0 + wave * 16 + (lg << 2) + r;
      atomicMax(&mk[row], fkey(m_ * DNORM));
    }
  }
}

// ---------- kvs (proj direct from global; grid x=16, 4 subs) ----------
__global__ __launch_bounds__(256) void kvs_accum_kernel(const float* __restrict__ qkf,
                                                        const USHORT* __restrict__ vb,
                                                        const USHORT* __restrict__ proj,
                                                        const float* __restrict__ diag_k,
                                                        const unsigned* __restrict__ mk,
                                                        float* __restrict__ kvs_ext) {
  __shared__ __align__(16) USHORT Ah[4096], Al[4096];
  __shared__ __align__(16) USHORT KpT[8192];   // [128][64]
  __shared__ __align__(16) USHORT Vt[5120];    // [80][64]
  const int t = threadIdx.x, lane = t & 63, wave = t >> 6;
  const int lr = lane & 15, lg = lane >> 4;
  const int bh = blockIdx.z, b = bh >> 4, h = bh & 15;
  const int fh = blockIdx.y;
  const int lstart = blockIdx.x * 256;
  const USHORT* projf = proj + (size_t)fh * 128 * 64;
  if (t < 64) {
#pragma unroll
    for (int r = 64; r < 80; ++r) Vt[r * 64 + t] = (r == 64) ? (USHORT)0x3F80 : (USHORT)0;
  }
  f32x4 acc2[2][5] = {};
  for (int sub = 0; sub < 4; ++sub) {
    const int row0 = lstart + sub * 64;
    const size_t grow0 = (size_t)b * 4096 + row0;
    {
      const int r = t >> 2, kc = (t & 3) * 16;
      stage_hl16(qkf + (grow0 + r) * 2048 + 1024 + h * 64 + kc, Ah, Al, r, kc);
    }
    {
      const int rv = t & 63, dc = (t >> 6) * 16;
      const USHORT* sv = vb + (grow0 + rv) * 1024 + h * 64 + dc;
      uint4 u0 = *(const uint4*)sv;
      uint4 u1 = *(const uint4*)(sv + 8);
      unsigned wsrc[8] = {u0.x, u0.y, u0.z, u0.w, u1.x, u1.y, u1.z, u1.w};
#pragma unroll
      for (int i = 0; i < 8; ++i) {
        const int d0 = dc + 2 * i;
        Vt[d0 * 64 + (rv ^ ((d0 & 7) << 3))] = (USHORT)(wsrc[i] & 0xffff);
        Vt[(d0 + 1) * 64 + (rv ^ (((d0 + 1) & 7) << 3))] = (USHORT)(wsrc[i] >> 16);
      }
    }
    __syncthreads();
    f32x4 acc1[8] = {};
#pragma unroll
    for (int ks = 0; ks < 2; ++ks) {
      const int koff = ks * 32 + (lg << 3);
      const int ar = wave * 16 + lr;
      short8 a_h = *(const short8*)&Ah[ar * 64 + (koff ^ ((ar & 7) << 3))];
      short8 a_l = *(const short8*)&Al[ar * 64 + (koff ^ ((ar & 7) << 3))];
#pragma unroll
      for (int n = 0; n < 8; ++n) {
        short8 b_h = *(const short8*)&projf[(n * 16 + lr) * 64 + koff];
        acc1[n] = __builtin_amdgcn_mfma_f32_16x16x32_bf16(a_h, b_h, acc1[n], 0, 0, 0);
        acc1[n] = __builtin_amdgcn_mfma_f32_16x16x32_bf16(a_l, b_h, acc1[n], 0, 0, 0);
      }
    }
    const int rbase = wave * 16 + (lg << 2);
    float dg[4], mkr[4];
#pragma unroll
    for (int r = 0; r < 4; ++r) {
      dg[r] = diag_k[(grow0 + rbase + r) * 16 + h];
      mkr[r] = keyf(mk[grow0 + rbase + r]);
    }
#pragma unroll
    for (int n = 0; n < 8; ++n) {
      const int col = n * 16 + lr;
      USHORT pk[4];
#pragma unroll
      for (int r = 0; r < 4; ++r)
        pk[r] = f2bf(__expf(acc1[n][r] * DNORM - dg[r] - mkr[r]) + 1e-6f);
      const unsigned w0 = (unsigned)pk[0] | ((unsigned)pk[1] << 16);
      const unsigned w1 = (unsigned)pk[2] | ((unsigned)pk[3] << 16);
      *(uint2*)&KpT[col * 64 + (rbase ^ ((col & 7) << 3))] = make_uint2(w0, w1);
    }
    __syncthreads();
#pragma unroll
    for (int ks = 0; ks < 2; ++ks) {
      const int koff = ks * 32 + (lg << 3);
      short8 af[2];
#pragma unroll
      for (int i = 0; i < 2; ++i) {
        const int m = wave * 32 + i * 16 + lr;
        af[i] = *(const short8*)&KpT[m * 64 + (koff ^ ((m & 7) << 3))];
      }
#pragma unroll
      for (int c = 0; c < 5; ++c) {
        const int d = c * 16 + lr;
        short8 bv = *(const short8*)&Vt[d * 64 + (koff ^ ((d & 7) << 3))];
#pragma unroll
        for (int i = 0; i < 2; ++i)
          acc2[i][c] = __builtin_amdgcn_mfma_f32_16x16x32_bf16(af[i], bv, acc2[i][c], 0, 0, 0);
      }
    }
    __syncthreads();
  }
  float* basep = kvs_ext + (size_t)bh * 20480 + (size_t)fh * 128 * 80;
#pragma unroll
  for (int i = 0; i < 2; ++i) {
    const int mrow = wave * 32 + i * 16 + (lg << 2);
#pragma unroll
    for (int c = 0; c < 5; ++c) {
      const int col = c * 16 + lr;
      if (c == 4 && lr != 0) continue;
#pragma unroll
      for (int r = 0; r < 4; ++r)
        atomicAdd(basep + (size_t)(mrow + r) * 80 + col, acc2[i][c][r]);
    }
  }
}

// ---------- kvs fp32 [bh][m][d] -> bf16 transposed [bh][d][m] ----------
__global__ __launch_bounds__(256) void cvt_kvs_kernel(const float* __restrict__ kvs_ext,
                                                      USHORT* __restrict__ kvsT16) {
  const int bh = blockIdx.x;
  const float* src = kvs_ext + (size_t)bh * 20480;
  USHORT* dst = kvsT16 + (size_t)bh * 20480;
  const int m = threadIdx.x;
#pragma unroll 8
  for (int d = 0; d < 80; ++d)
    dst[d * 256 + m] = f2bf(src[m * 80 + d]);
}

// ---------- qav (proj + kvsT16 direct from global; LDS 32 KB) ----------
__global__ __launch_bounds__(256) void qav_kernel(const float* __restrict__ qkf,
                                                  const USHORT* __restrict__ proj,
                                                  const float* __restrict__ diag_q,
                                                  const USHORT* __restrict__ kvsT16,
                                                  USHORT* __restrict__ avb) {
  __shared__ __align__(16) USHORT smem[16384];  // 32 KB
  USHORT* Ah = smem;            // [64][64]
  USHORT* Al = smem + 4096;     // [64][64]
  USHORT* Qp = smem;            // [64][256] swz (aliases Ah/Al after dd)
  const int t = threadIdx.x, lane = t & 63, wave = t >> 6;
  const int lr = lane & 15, lg = lane >> 4;
  const int bh = blockIdx.y, b = bh >> 4, h = bh & 15;
  const size_t grow0 = (size_t)b * 4096 + blockIdx.x * 64;
  const USHORT* kvsrc = kvsT16 + (size_t)bh * 20480;
  {
    const int r = t >> 2, kc = (t & 3) * 16;
    stage_hl16(qkf + (grow0 + r) * 2048 + h * 64 + kc, Ah, Al, r, kc);
  }
  __syncthreads();
  f32x4 acc1[16] = {};
#pragma unroll
  for (int ks = 0; ks < 2; ++ks) {
    const int koff = ks * 32 + (lg << 3);
    const int ar = wave * 16 + lr;
    short8 a_h = *(const short8*)&Ah[ar * 64 + (koff ^ ((ar & 7) << 3))];
    short8 a_l = *(const short8*)&Al[ar * 64 + (koff ^ ((ar & 7) << 3))];
#pragma unroll
    for (int n = 0; n < 16; ++n) {
      short8 b_h = *(const short8*)&proj[(n * 16 + lr) * 64 + koff];
      acc1[n] = __builtin_amdgcn_mfma_f32_16x16x32_bf16(a_h, b_h, acc1[n], 0, 0, 0);
      acc1[n] = __builtin_amdgcn_mfma_f32_16x16x32_bf16(a_l, b_h, acc1[n], 0, 0, 0);
    }
  }
  __syncthreads();  // Ah/Al now dead; safe to overlay Qp
  const int rbase = wave * 16 + (lg << 2);
  float dg[4], mx[4];
#pragma unroll
  for (int r = 0; r < 4; ++r) dg[r] = diag_q[(grow0 + rbase + r) * 16 + h];
#pragma unroll
  for (int r = 0; r < 4; ++r) {
    float m_ = acc1[0][r];
#pragma unroll
    for (int n = 1; n < 16; ++n) m_ = fmaxf(m_, acc1[n][r]);
    m_ = fmaxf(m_, __shfl_xor(m_, 1));
    m_ = fmaxf(m_, __shfl_xor(m_, 2));
    m_ = fmaxf(m_, __shfl_xor(m_, 4));
    m_ = fmaxf(m_, __shfl_xor(m_, 8));
    mx[r] = m_ * DNORM;
  }
#pragma unroll
  for (int n = 0; n < 16; ++n) {
    const int col = n * 16 + lr;
#pragma unroll
    for (int r = 0; r < 4; ++r) {
      const int row = rbase + r;
      Qp[row * 256 + (col ^ ((row & 7) << 3))] =
          f2bf(__expf(acc1[n][r] * DNORM - dg[r] - mx[r]) + 1e-6f);
    }
  }
  __syncthreads();
  f32x4 acc2[5] = {};
#pragma unroll
  for (int ks2 = 0; ks2 < 8; ++ks2) {
    const int koff = ks2 * 32 + (lg << 3);
    const int ar = wave * 16 + lr;
    short8 a = *(const short8*)&Qp[ar * 256 + (koff ^ ((ar & 7) << 3))];
#pragma unroll
    for (int c = 0; c < 5; ++c) {
      short8 bv = *(const short8*)&kvsrc[(c * 16 + lr) * 256 + koff];
      acc2[c] = __builtin_amdgcn_mfma_f32_16x16x32_bf16(a, bv, acc2[c], 0, 0, 0);
    }
  }
#pragma unroll
  for (int r = 0; r < 4; ++r) {
    const float den = __shfl(acc2[4][r], (lane & 48));
#pragma unroll
    for (int c = 0; c < 4; ++c) {
      const float o = acc2[c][r] / den;
      avb[(grow0 + rbase + r) * 1024 + h * 64 + c * 16 + lr] = f2bf(o);
    }
  }
}

// ---------- launch ----------
extern "C" void kernel_launch(void* const* d_in, const int* in_sizes, int n_in,
                              void* d_out, int out_size, void* d_ws, size_t ws_size,
                              hipStream_t stream) {
  char* ws = (char*)d_ws;

  const size_t OFF_FLAG = 0;                       // 256
  const size_t OFF_WQKVT = 256;                    // 6,291,456
  const size_t OFF_WOT = OFF_WQKVT + 6291456;      // 2,097,152
  const size_t OFF_PROJC = OFF_WOT + 2097152;      // 32,768
  const size_t OFF_PAD = OFF_PROJC + 32768;        // 524,288 (unused)
  const size_t OFF_XH = OFF_PAD + 524288;          // 16,777,216 (reused as av)
  const size_t OFF_SINUT = OFF_XH + 16777216;      // 1,048,576 fp32 sin/cos tables
  const size_t OFF_PAD2 = OFF_SINUT + 1048576;     // 15,728,640 (unused)
  const size_t OFF_QKF = OFF_PAD2 + 15728640;      // 67,108,864 (8192x2048 fp32 rotated q,k)
  const size_t OFF_VB = OFF_QKF + 67108864;        // 16,777,216 (8192x1024 bf16 v)
  const size_t OFF_DIAGQ = OFF_VB + 16777216;      // 524,288
  const size_t OFF_DIAGK = OFF_DIAGQ + 524288;     // 524,288
  const size_t OFF_MK = OFF_DIAGK + 524288;        // 32,768
  const size_t OFF_KVS = OFF_MK + 32768;           // 2,621,440
  const size_t OFF_KVST = OFF_KVS + 2621440;       // 1,310,720

  int* flag = (int*)(ws + OFF_FLAG);
  USHORT* wqkvt = (USHORT*)(ws + OFF_WQKVT);
  USHORT* wot = (USHORT*)(ws + OFF_WOT);
  USHORT* projc = (USHORT*)(ws + OFF_PROJC);
  USHORT* xh = (USHORT*)(ws + OFF_XH);
  USHORT* avb = (USHORT*)(ws + OFF_XH);  // alias: xh dead after gemm1
  float* sinuT = (float*)(ws + OFF_SINUT);
  float* qkf = (float*)(ws + OFF_QKF);
  USHORT* vb = (USHORT*)(ws + OFF_VB);
  float* diagq = (float*)(ws + OFF_DIAGQ);
  float* diagk = (float*)(ws + OFF_DIAGK);
  unsigned* mk = (unsigned*)(ws + OFF_MK);
  float* kvsb = (float*)(ws + OFF_KVS);
  USHORT* kvst = (USHORT*)(ws + OFF_KVST);

  hipMemsetAsync(ws + OFF_FLAG, 0, 256, stream);
  hipMemsetAsync(ws + OFF_MK, 0, 32768, stream);
  hipMemsetAsync(ws + OFF_KVS, 0, 2621440, stream);

  detect_kernel<<<1, 256, 0, stream>>>((const USHORT*)d_in[1], flag);
  cvt_x_kernel<<<4112, 256, 0, stream>>>(d_in[0], xh, d_in[5], projc, flag);
  sinut_kernel<<<16, 256, 0, stream>>>(d_in[6], sinuT, flag);
  transpose_w_kernel<<<dim3(16, 16, 4), 256, 0, stream>>>(d_in[1], d_in[2], d_in[3], d_in[4],
                                                          wqkvt, wot, flag);
  gemm_bt<true, false><<<dim3(24, 64), 256, 0, stream>>>(
      xh, wqkvt, qkf, vb, sinuT, diagq, diagk,
      8192, 3072, 1024, 1024, 1024, 2048, 1024, 2048, flag);
  ddk_max_kernel<<<dim3(64, 32), 256, 0, stream>>>(qkf, projc, mk);
  kvs_accum_kernel<<<dim3(16, 2, 32), 256, 0, stream>>>(qkf, vb, projc, diagk, mk, kvsb);
  cvt_kvs_kernel<<<32, 256, 0, stream>>>(kvsb, kvst);
  qav_kernel<<<dim3(64, 32), 256, 0, stream>>>(qkf, projc, diagq, kvst, avb);
  gemm_bt<false, true><<<dim3(8, 64), 256, 0, stream>>>(
      avb, wot, d_out, nullptr, nullptr, nullptr, nullptr,
      8192, 1024, 1024, 1024, 1024, 1024, 0, 0, flag);
}

// Round 10
// 244.018 us; speedup vs baseline: 1.2990x; 1.2990x over previous
//
#include <hip/hip_runtime.h>

typedef __attribute__((ext_vector_type(8))) short short8;
typedef __attribute__((ext_vector_type(4))) float f32x4;
typedef unsigned short USHORT;

#define DNORM 0.35355339059327373f  // 64^-0.25
#define AS1(p) ((const __attribute__((address_space(1))) void*)(p))
#define AS3(p) ((__attribute__((address_space(3))) void*)(p))

// ---------- helpers ----------
__device__ __forceinline__ USHORT f2bf(float f) {
  union { float f; unsigned u; } v; v.f = f;
  unsigned r = v.u + 0x7fffu + ((v.u >> 16) & 1u);
  return (USHORT)(r >> 16);
}
__device__ __forceinline__ float bf2f(USHORT u) {
  union { unsigned u; float f; } v; v.u = ((unsigned)u) << 16;
  return v.f;
}
__device__ __forceinline__ unsigned fkey(float f) {
  union { float f; unsigned u; } v; v.f = f;
  return (v.u & 0x80000000u) ? ~v.u : (v.u | 0x80000000u);
}
__device__ __forceinline__ float keyf(unsigned k) {
  union { unsigned u; float f; } v;
  v.u = (k & 0x80000000u) ? (k ^ 0x80000000u) : ~k;
  return v.f;
}

// stage 16 fp32 -> hi/lo bf16 into swizzled LDS rows (shared by ddk/kvs/qav)
__device__ __forceinline__ void stage_hl16(const float* __restrict__ src,
                                           USHORT* __restrict__ Ah, USHORT* __restrict__ Al,
                                           int r, int kc) {
  float b[16];
  *(float4*)&b[0] = *(const float4*)(src);
  *(float4*)&b[4] = *(const float4*)(src + 4);
  *(float4*)&b[8] = *(const float4*)(src + 8);
  *(float4*)&b[12] = *(const float4*)(src + 12);
  const int swz = (r & 7) << 3;
  unsigned H[8], L[8];
#pragma unroll
  for (int p = 0; p < 8; ++p) {
    USHORT h0 = f2bf(b[2 * p]), h1 = f2bf(b[2 * p + 1]);
    USHORT l0 = f2bf(b[2 * p] - bf2f(h0)), l1 = f2bf(b[2 * p + 1] - bf2f(h1));
    H[p] = (unsigned)h0 | ((unsigned)h1 << 16);
    L[p] = (unsigned)l0 | ((unsigned)l1 << 16);
  }
  *(uint4*)&Ah[r * 64 + (kc ^ swz)] = make_uint4(H[0], H[1], H[2], H[3]);
  *(uint4*)&Ah[r * 64 + ((kc + 8) ^ swz)] = make_uint4(H[4], H[5], H[6], H[7]);
  *(uint4*)&Al[r * 64 + (kc ^ swz)] = make_uint4(L[0], L[1], L[2], L[3]);
  *(uint4*)&Al[r * 64 + ((kc + 8) ^ swz)] = make_uint4(L[4], L[5], L[6], L[7]);
}

// ---------- dtype detect: bf16-view of fp32 data has huge-exponent junk ----------
__global__ __launch_bounds__(256) void detect_kernel(const USHORT* __restrict__ w,
                                                     int* __restrict__ flag) {
  const int t = threadIdx.x;
  unsigned mx = 0;
#pragma unroll 8
  for (int c = 0; c < 64; ++c) {
    unsigned a = (unsigned)w[c * 256 + t] & 0x7FFFu;
    if (a > mx) mx = a;
  }
  if (mx > 0x4480u) atomicOr(flag, 1);
}

// ---------- x -> bf16; also proj+sinu convert ----------
__global__ __launch_bounds__(256) void cvt_x_kernel(const void* __restrict__ xin,
                                                    USHORT* __restrict__ xh,
                                                    const void* __restrict__ proj,
                                                    const void* __restrict__ sinu,
                                                    USHORT* __restrict__ projc,
                                                    USHORT* __restrict__ sinuc,
                                                    const int* __restrict__ flag) {
  if (blockIdx.x >= 4096) {  // proj+sinu tail
    const int i = ((blockIdx.x - 4096) * 256 + threadIdx.x) * 4;
    const int isp = (i < 16384);
    const int off = isp ? i : (i - 16384);
    const void* src = isp ? proj : sinu;
    USHORT* dst = isp ? projc : sinuc;
    if (*flag) {
      float4 v = *(const float4*)((const float*)src + off);
      USHORT a = f2bf(v.x), b = f2bf(v.y), c = f2bf(v.z), d = f2bf(v.w);
      *(uint2*)(dst + off) = make_uint2((unsigned)a | ((unsigned)b << 16),
                                        (unsigned)c | ((unsigned)d << 16));
    } else {
      *(uint2*)(dst + off) = *(const uint2*)((const USHORT*)src + off);
    }
    return;
  }
  const size_t i = ((size_t)blockIdx.x * 256 + threadIdx.x) * 8;
  if (*flag) {
    const float* xf = (const float*)xin;
    float4 a = *(const float4*)(xf + i);
    float4 b = *(const float4*)(xf + i + 4);
    float c[8] = {a.x, a.y, a.z, a.w, b.x, b.y, b.z, b.w};
    unsigned ho[4];
#pragma unroll
    for (int j = 0; j < 4; ++j) {
      USHORT h0 = f2bf(c[2 * j]), h1 = f2bf(c[2 * j + 1]);
      ho[j] = (unsigned)h0 | ((unsigned)h1 << 16);
    }
    *(uint4*)(xh + i) = make_uint4(ho[0], ho[1], ho[2], ho[3]);
  } else {
    uint4 u = *(const uint4*)((const USHORT*)xin + i);
    *(uint4*)(xh + i) = u;
  }
}

// ---------- transpose W (1024x1024 -> bf16 transposed), dtype-adaptive ----------
__global__ __launch_bounds__(256) void transpose_w_kernel(const void* __restrict__ Wq,
                                                          const void* __restrict__ Wk,
                                                          const void* __restrict__ Wv,
                                                          const void* __restrict__ Wo,
                                                          USHORT* __restrict__ wqkvt,
                                                          USHORT* __restrict__ wot,
                                                          const int* __restrict__ flag) {
  __shared__ __align__(16) USHORT tile[64][80];
  const int z = blockIdx.z;
  const void* src = (z == 0) ? Wq : (z == 1) ? Wk : (z == 2) ? Wv : Wo;
  USHORT* dst = (z < 3) ? (wqkvt + (size_t)z * 1048576) : wot;
  const int r0 = blockIdx.y * 64, c0 = blockIdx.x * 64;
  const int t = threadIdx.x;
  const int rr = t >> 2, c4 = (t & 3) * 16;
  if (*flag) {
    const float* s = (const float*)src + (size_t)(r0 + rr) * 1024 + c0 + c4;
#pragma unroll
    for (int i = 0; i < 4; ++i) {
      float4 v = *(const float4*)(s + i * 4);
      tile[rr][c4 + i * 4 + 0] = f2bf(v.x);
      tile[rr][c4 + i * 4 + 1] = f2bf(v.y);
      tile[rr][c4 + i * 4 + 2] = f2bf(v.z);
      tile[rr][c4 + i * 4 + 3] = f2bf(v.w);
    }
  } else {
    const USHORT* s = (const USHORT*)src + (size_t)(r0 + rr) * 1024 + c0 + c4;
    *(uint4*)&tile[rr][c4] = *(const uint4*)s;
    *(uint4*)&tile[rr][c4 + 8] = *(const uint4*)(s + 8);
  }
  __syncthreads();
  USHORT tmp[16];
#pragma unroll
  for (int i = 0; i < 16; ++i) tmp[i] = tile[c4 + i][rr];
  uint4 o0, o1;
  o0.x = (unsigned)tmp[0] | ((unsigned)tmp[1] << 16);
  o0.y = (unsigned)tmp[2] | ((unsigned)tmp[3] << 16);
  o0.z = (unsigned)tmp[4] | ((unsigned)tmp[5] << 16);
  o0.w = (unsigned)tmp[6] | ((unsigned)tmp[7] << 16);
  o1.x = (unsigned)tmp[8] | ((unsigned)tmp[9] << 16);
  o1.y = (unsigned)tmp[10] | ((unsigned)tmp[11] << 16);
  o1.z = (unsigned)tmp[12] | ((unsigned)tmp[13] << 16);
  o1.w = (unsigned)tmp[14] | ((unsigned)tmp[15] << 16);
  USHORT* d = dst + (size_t)(c0 + rr) * 1024 + r0 + c4;
  *(uint4*)d = o0;
  *(uint4*)(d + 8) = o1;
}

// ---------- GEMM: C(MxN) = A(MxK) @ Bt(NxK)^T, global_load_lds + XOR swizzle ----------
// XCD-aware bijective block swizzle (grid count % 8 == 0).
// ROTEPI: cols < NLO -> rotate fp32, store fp32 + diag; cols >= NLO -> bf16 to Vb.
// FLAGOUT: store fp32 when *flag else bf16 (gemm2).
template <bool ROTEPI, bool FLAGOUT>
__global__ __launch_bounds__(256) void gemm_bt(const USHORT* __restrict__ A,
                                               const USHORT* __restrict__ Bt,
                                               void* __restrict__ Cv,
                                               USHORT* __restrict__ Vb,
                                               const USHORT* __restrict__ sinu,
                                               float* __restrict__ diag_q,
                                               float* __restrict__ diag_k,
                                               int M, int N, int K, int lda, int ldb, int ldc,
                                               int ldv, int NLO, const int* __restrict__ flag) {
  __shared__ __align__(16) USHORT As[8192];   // [128][64] swizzled
  __shared__ __align__(16) USHORT Bs[8192];   // [128][64] swizzled
  const int fl = *flag;
  const int t = threadIdx.x;
  const int lane = t & 63, wave = t >> 6;
  const int lr = lane & 15, lg = lane >> 4;
  const int nwg = gridDim.x * gridDim.y;
  const int orig = blockIdx.y * gridDim.x + blockIdx.x;
  const int tile = (orig & 7) * (nwg >> 3) + (orig >> 3);
  const int bx = tile % gridDim.x, by = tile / gridDim.x;
  const int row0 = by * 128, col0 = bx * 128;
  const int wr = (wave >> 1) * 64, wc = (wave & 1) * 64;
  f32x4 acc[4][4] = {};
  for (int k0 = 0; k0 < K; k0 += 64) {
#pragma unroll
    for (int c = 0; c < 4; ++c) {
      const int e = c * 256 + t;
      const int r = e >> 3;                       // logical row 0..127
      const int ch = (t & 7) ^ (r & 7);           // inverse-swizzled source chunk
      const size_t goffA = (size_t)(row0 + r) * lda + k0 + ch * 8;
      const size_t goffB = (size_t)(col0 + r) * ldb + k0 + ch * 8;
      __builtin_amdgcn_global_load_lds(AS1(A + goffA), AS3(&As[c * 2048 + wave * 512]), 16, 0, 0);
      __builtin_amdgcn_global_load_lds(AS1(Bt + goffB), AS3(&Bs[c * 2048 + wave * 512]), 16, 0, 0);
    }
    __syncthreads();
#pragma unroll
    for (int ks = 0; ks < 2; ++ks) {
      const int koff = ks * 32 + (lg << 3);
      short8 av_[4], bv[4];
#pragma unroll
      for (int i = 0; i < 4; ++i) {
        const int ar = wr + i * 16 + lr;
        av_[i] = *(const short8*)&As[ar * 64 + (koff ^ ((ar & 7) << 3))];
      }
#pragma unroll
      for (int j = 0; j < 4; ++j) {
        const int br = wc + j * 16 + lr;
        bv[j] = *(const short8*)&Bs[br * 64 + (koff ^ ((br & 7) << 3))];
      }
#pragma unroll
      for (int i = 0; i < 4; ++i)
#pragma unroll
        for (int j = 0; j < 4; ++j)
          acc[i][j] = __builtin_amdgcn_mfma_f32_16x16x32_bf16(av_[i], bv[j], acc[i][j], 0, 0, 0);
    }
    __syncthreads();
  }
  if constexpr (ROTEPI) {
    if (col0 < NLO) {
      // q/k region: rotate fp32, store fp32, diag
      const int G0 = col0 + wc;          // wave's head base col (64-wide = 1 head)
      const int which = G0 >> 10;        // 0=q, 1=k
      const int h = (G0 & 1023) >> 6;
      float* qk = (float*)Cv;
#pragma unroll
      for (int i = 0; i < 4; ++i) {
        float ss[4] = {0.f, 0.f, 0.f, 0.f};
#pragma unroll
        for (int j = 0; j < 4; ++j) {
          const int G = G0 + j * 16 + lr;
          const int d = G & 63;
          const int j2 = d >> 1;
#pragma unroll
          for (int r = 0; r < 4; ++r) {
            const int R = row0 + wr + i * 16 + (lg << 2) + r;
            const int l = R & 4095;
            const float own = acc[i][j][r];
            const float oth = __shfl_xor(own, 1);
            const float s = bf2f(sinu[l * 64 + j2]);
            const float co = bf2f(sinu[l * 64 + 32 + j2]);
            const float ro = (d & 1) ? (own * co + oth * s) : (own * co - oth * s);
            ss[r] += ro * ro;
            qk[(size_t)R * ldc + G] = ro;
          }
        }
#pragma unroll
        for (int r = 0; r < 4; ++r) {
          float v_ = ss[r];
          v_ += __shfl_xor(v_, 1);
          v_ += __shfl_xor(v_, 2);
          v_ += __shfl_xor(v_, 4);
          v_ += __shfl_xor(v_, 8);
          if (lr == 0) {
            const int R = row0 + wr + i * 16 + (lg << 2) + r;
            (which ? diag_k : diag_q)[R * 16 + h] = v_ * 0.0625f;  // 0.5*DNORM^2
          }
        }
      }
    } else {
      // V region: bf16 store to compact v buffer
#pragma unroll
      for (int i = 0; i < 4; ++i) {
#pragma unroll
        for (int r = 0; r < 4; ++r) {
          const int row = row0 + wr + i * 16 + (lg << 2) + r;
#pragma unroll
          for (int j = 0; j < 4; ++j) {
            const int col = col0 + wc + j * 16 + lr - NLO;
            Vb[(size_t)row * ldv + col] = f2bf(acc[i][j][r]);
          }
        }
      }
    }
    return;
  }
#pragma unroll
  for (int i = 0; i < 4; ++i) {
#pragma unroll
    for (int r = 0; r < 4; ++r) {
      const int row = row0 + wr + i * 16 + (lg << 2) + r;
#pragma unroll
      for (int j = 0; j < 4; ++j) {
        const int col = col0 + wc + j * 16 + lr;
        const float v = acc[i][j][r];
        if constexpr (FLAGOUT) {
          if (fl) ((float*)Cv)[(size_t)row * ldc + col] = v;
          else ((USHORT*)Cv)[(size_t)row * ldc + col] = f2bf(v);
        } else {
          ((USHORT*)Cv)[(size_t)row * ldc + col] = f2bf(v);
        }
      }
    }
  }
}

// ---------- ddk max over (h, m) per (b, l): atomicMax into mk[row] ----------
__global__ __launch_bounds__(256) void ddk_max_kernel(const float* __restrict__ qkf,
                                                      const USHORT* __restrict__ proj,
                                                      unsigned* __restrict__ mk) {
  __shared__ __align__(16) USHORT Ph[16384];
  __shared__ __align__(16) USHORT Ah[4096], Al[4096];
  const int t = threadIdx.x, lane = t & 63, wave = t >> 6;
  const int lr = lane & 15, lg = lane >> 4;
  const int bh = blockIdx.y, b = bh >> 4, h = bh & 15;
  const size_t grow0 = (size_t)b * 4096 + blockIdx.x * 64;
  {
#pragma unroll
    for (int c = 0; c < 8; ++c)
      *(uint4*)&Ph[t * 64 + ((c ^ (t & 7)) << 3)] = *(const uint4*)(proj + t * 64 + c * 8);
  }
  {
    const int r = t >> 2, kc = (t & 3) * 16;
    stage_hl16(qkf + (grow0 + r) * 2048 + 1024 + h * 64 + kc, Ah, Al, r, kc);
  }
  __syncthreads();
  f32x4 acc[16] = {};
#pragma unroll
  for (int ks = 0; ks < 2; ++ks) {
    const int koff = ks * 32 + (lg << 3);
    const int ar = wave * 16 + lr;
    short8 a_h = *(const short8*)&Ah[ar * 64 + (koff ^ ((ar & 7) << 3))];
    short8 a_l = *(const short8*)&Al[ar * 64 + (koff ^ ((ar & 7) << 3))];
#pragma unroll
    for (int n = 0; n < 16; ++n) {
      const int br = n * 16 + lr;
      short8 b_h = *(const short8*)&Ph[br * 64 + (koff ^ ((br & 7) << 3))];
      acc[n] = __builtin_amdgcn_mfma_f32_16x16x32_bf16(a_h, b_h, acc[n], 0, 0, 0);
      acc[n] = __builtin_amdgcn_mfma_f32_16x16x32_bf16(a_l, b_h, acc[n], 0, 0, 0);
    }
  }
#pragma unroll
  for (int r = 0; r < 4; ++r) {
    float m_ = acc[0][r];
#pragma unroll
    for (int n = 1; n < 16; ++n) m_ = fmaxf(m_, acc[n][r]);
    m_ = fmaxf(m_, __shfl_xor(m_, 1));
    m_ = fmaxf(m_, __shfl_xor(m_, 2));
    m_ = fmaxf(m_, __shfl_xor(m_, 4));
    m_ = fmaxf(m_, __shfl_xor(m_, 8));
    if (lr == 0) {
      const int row = (int)grow0 + wave * 16 + (lg << 2) + r;
      atomicMax(&mk[row], fkey(m_ * DNORM));
    }
  }
}

// ---------- kp = exp(ddk*DN - diag - mk) + EPS; kvs_ext += kp^T @ [v | 1] ----------
__global__ __launch_bounds__(256) void kvs_accum_kernel(const float* __restrict__ qkf,
                                                        const USHORT* __restrict__ vb,
                                                        const USHORT* __restrict__ proj,
                                                        const float* __restrict__ diag_k,
                                                        const unsigned* __restrict__ mk,
                                                        float* __restrict__ kvs_ext) {
  __shared__ __align__(16) USHORT Ph[8192];    // [128][64]
  __shared__ __align__(16) USHORT Ah[4096], Al[4096];
  __shared__ __align__(16) USHORT KpT[8192];   // [128][64]
  __shared__ __align__(16) USHORT Vt[5120];    // [80][64]
  const int t = threadIdx.x, lane = t & 63, wave = t >> 6;
  const int lr = lane & 15, lg = lane >> 4;
  const int bh = blockIdx.z, b = bh >> 4, h = bh & 15;
  const int fh = blockIdx.y;
  const int lstart = blockIdx.x * 512;
  {
    const int pr = t >> 1;
    const USHORT* src = proj + (size_t)(fh * 128 + pr) * 64;
#pragma unroll
    for (int c = 0; c < 4; ++c) {
      const int ch = (t & 1) * 4 + c;
      *(uint4*)&Ph[pr * 64 + ((ch ^ (pr & 7)) << 3)] = *(const uint4*)(src + ch * 8);
    }
  }
  if (t < 64) {
#pragma unroll
    for (int r = 64; r < 80; ++r) Vt[r * 64 + t] = (r == 64) ? (USHORT)0x3F80 : (USHORT)0;
  }
  f32x4 acc2[2][5] = {};
  for (int sub = 0; sub < 8; ++sub) {
    const int row0 = lstart + sub * 64;
    const size_t grow0 = (size_t)b * 4096 + row0;
    {
      const int r = t >> 2, kc = (t & 3) * 16;
      stage_hl16(qkf + (grow0 + r) * 2048 + 1024 + h * 64 + kc, Ah, Al, r, kc);
    }
    {
      const int rv = t & 63, dc = (t >> 6) * 16;
      const USHORT* sv = vb + (grow0 + rv) * 1024 + h * 64 + dc;
      uint4 u0 = *(const uint4*)sv;
      uint4 u1 = *(const uint4*)(sv + 8);
      unsigned wsrc[8] = {u0.x, u0.y, u0.z, u0.w, u1.x, u1.y, u1.z, u1.w};
#pragma unroll
      for (int i = 0; i < 8; ++i) {
        const int d0 = dc + 2 * i;
        Vt[d0 * 64 + (rv ^ ((d0 & 7) << 3))] = (USHORT)(wsrc[i] & 0xffff);
        Vt[(d0 + 1) * 64 + (rv ^ (((d0 + 1) & 7) << 3))] = (USHORT)(wsrc[i] >> 16);
      }
    }
    __syncthreads();
    f32x4 acc1[8] = {};
#pragma unroll
    for (int ks = 0; ks < 2; ++ks) {
      const int koff = ks * 32 + (lg << 3);
      const int ar = wave * 16 + lr;
      short8 a_h = *(const short8*)&Ah[ar * 64 + (koff ^ ((ar & 7) << 3))];
      short8 a_l = *(const short8*)&Al[ar * 64 + (koff ^ ((ar & 7) << 3))];
#pragma unroll
      for (int n = 0; n < 8; ++n) {
        const int br = n * 16 + lr;
        short8 b_h = *(const short8*)&Ph[br * 64 + (koff ^ ((br & 7) << 3))];
        acc1[n] = __builtin_amdgcn_mfma_f32_16x16x32_bf16(a_h, b_h, acc1[n], 0, 0, 0);
        acc1[n] = __builtin_amdgcn_mfma_f32_16x16x32_bf16(a_l, b_h, acc1[n], 0, 0, 0);
      }
    }
    const int rbase = wave * 16 + (lg << 2);
    float dg[4], mkr[4];
#pragma unroll
    for (int r = 0; r < 4; ++r) {
      dg[r] = diag_k[(grow0 + rbase + r) * 16 + h];
      mkr[r] = keyf(mk[grow0 + rbase + r]);
    }
#pragma unroll
    for (int n = 0; n < 8; ++n) {
      const int col = n * 16 + lr;
      USHORT pk[4];
#pragma unroll
      for (int r = 0; r < 4; ++r)
        pk[r] = f2bf(__expf(acc1[n][r] * DNORM - dg[r] - mkr[r]) + 1e-6f);
      const unsigned w0 = (unsigned)pk[0] | ((unsigned)pk[1] << 16);
      const unsigned w1 = (unsigned)pk[2] | ((unsigned)pk[3] << 16);
      *(uint2*)&KpT[col * 64 + (rbase ^ ((col & 7) << 3))] = make_uint2(w0, w1);
    }
    __syncthreads();
#pragma unroll
    for (int ks = 0; ks < 2; ++ks) {
      const int koff = ks * 32 + (lg << 3);
      short8 af[2];
#pragma unroll
      for (int i = 0; i < 2; ++i) {
        const int m = wave * 32 + i * 16 + lr;
        af[i] = *(const short8*)&KpT[m * 64 + (koff ^ ((m & 7) << 3))];
      }
#pragma unroll
      for (int c = 0; c < 5; ++c) {
        const int d = c * 16 + lr;
        short8 bv = *(const short8*)&Vt[d * 64 + (koff ^ ((d & 7) << 3))];
#pragma unroll
        for (int i = 0; i < 2; ++i)
          acc2[i][c] = __builtin_amdgcn_mfma_f32_16x16x32_bf16(af[i], bv, acc2[i][c], 0, 0, 0);
      }
    }
    __syncthreads();
  }
  float* basep = kvs_ext + (size_t)bh * 20480 + (size_t)fh * 128 * 80;
#pragma unroll
  for (int i = 0; i < 2; ++i) {
    const int mrow = wave * 32 + i * 16 + (lg << 2);
#pragma unroll
    for (int c = 0; c < 5; ++c) {
      const int col = c * 16 + lr;
      if (c == 4 && lr != 0) continue;
#pragma unroll
      for (int r = 0; r < 4; ++r)
        atomicAdd(basep + (size_t)(mrow + r) * 80 + col, acc2[i][c][r]);
    }
  }
}

// ---------- qp = exp(ddq*DN - diag - rowmax)+EPS; av = (qp@[kvs|ks])/den ----------
// Btl staged directly from fp32 kvs_ext (cvt fused into staging).
__global__ __launch_bounds__(256) void qav_kernel(const float* __restrict__ qkf,
                                                  const USHORT* __restrict__ proj,
                                                  const float* __restrict__ diag_q,
                                                  const float* __restrict__ kvsb,
                                                  USHORT* __restrict__ avb) {
  __shared__ __align__(16) USHORT smem[36864];
  USHORT* Ph = smem;            // [256][64] swz
  USHORT* Qp = smem;            // [64][256] swz (aliases Ph)
  USHORT* Ah = smem + 16384;    // [64][64]
  USHORT* Al = smem + 20480;    // [64][64]
  USHORT* Btl = smem + 16384;   // [80][256] swz (aliases Ah/Al)
  const int t = threadIdx.x, lane = t & 63, wave = t >> 6;
  const int lr = lane & 15, lg = lane >> 4;
  const int bh = blockIdx.y, b = bh >> 4, h = bh & 15;
  const size_t grow0 = (size_t)b * 4096 + blockIdx.x * 64;
  {
#pragma unroll
    for (int c = 0; c < 8; ++c)
      *(uint4*)&Ph[t * 64 + ((c ^ (t & 7)) << 3)] = *(const uint4*)(proj + t * 64 + c * 8);
  }
  {
    const int r = t >> 2, kc = (t & 3) * 16;
    stage_hl16(qkf + (grow0 + r) * 2048 + h * 64 + kc, Ah, Al, r, kc);
  }
  __syncthreads();
  f32x4 acc1[16] = {};
#pragma unroll
  for (int ks = 0; ks < 2; ++ks) {
    const int koff = ks * 32 + (lg << 3);
    const int ar = wave * 16 + lr;
    short8 a_h = *(const short8*)&Ah[ar * 64 + (koff ^ ((ar & 7) << 3))];
    short8 a_l = *(const short8*)&Al[ar * 64 + (koff ^ ((ar & 7) << 3))];
#pragma unroll
    for (int n = 0; n < 16; ++n) {
      const int br = n * 16 + lr;
      short8 b_h = *(const short8*)&Ph[br * 64 + (koff ^ ((br & 7) << 3))];
      acc1[n] = __builtin_amdgcn_mfma_f32_16x16x32_bf16(a_h, b_h, acc1[n], 0, 0, 0);
      acc1[n] = __builtin_amdgcn_mfma_f32_16x16x32_bf16(a_l, b_h, acc1[n], 0, 0, 0);
    }
  }
  __syncthreads();  // Ph/Ah/Al now dead; safe to overlay Qp/Btl
  {
    const float* src = kvsb + (size_t)bh * 20480;
#pragma unroll
    for (int cc = 0; cc < 20; ++cc) {
      const int e0 = cc * 1024 + t * 4;
      float4 v = *(const float4*)(src + e0);
      const int m = e0 / 80, c0 = e0 % 80;
      float comp[4] = {v.x, v.y, v.z, v.w};
#pragma unroll
      for (int i = 0; i < 4; ++i) {
        const int c = c0 + i;
        Btl[c * 256 + (m ^ ((c & 7) << 3))] = f2bf(comp[i]);
      }
    }
  }
  const int rbase = wave * 16 + (lg << 2);
  float dg[4], mx[4];
#pragma unroll
  for (int r = 0; r < 4; ++r) dg[r] = diag_q[(grow0 + rbase + r) * 16 + h];
#pragma unroll
  for (int r = 0; r < 4; ++r) {
    float m_ = acc1[0][r];
#pragma unroll
    for (int n = 1; n < 16; ++n) m_ = fmaxf(m_, acc1[n][r]);
    m_ = fmaxf(m_, __shfl_xor(m_, 1));
    m_ = fmaxf(m_, __shfl_xor(m_, 2));
    m_ = fmaxf(m_, __shfl_xor(m_, 4));
    m_ = fmaxf(m_, __shfl_xor(m_, 8));
    mx[r] = m_ * DNORM;
  }
#pragma unroll
  for (int n = 0; n < 16; ++n) {
    const int col = n * 16 + lr;
#pragma unroll
    for (int r = 0; r < 4; ++r) {
      const int row = rbase + r;
      Qp[row * 256 + (col ^ ((row & 7) << 3))] =
          f2bf(__expf(acc1[n][r] * DNORM - dg[r] - mx[r]) + 1e-6f);
    }
  }
  __syncthreads();
  f32x4 acc2[5] = {};
#pragma unroll
  for (int ks2 = 0; ks2 < 8; ++ks2) {
    const int koff = ks2 * 32 + (lg << 3);
    const int ar = wave * 16 + lr;
    short8 a = *(const short8*)&Qp[ar * 256 + (koff ^ ((ar & 7) << 3))];
#pragma unroll
    for (int c = 0; c < 5; ++c) {
      const int cr = c * 16 + lr;
      short8 bv = *(const short8*)&Btl[cr * 256 + (koff ^ ((cr & 7) << 3))];
      acc2[c] = __builtin_amdgcn_mfma_f32_16x16x32_bf16(a, bv, acc2[c], 0, 0, 0);
    }
  }
#pragma unroll
  for (int r = 0; r < 4; ++r) {
    const float den = __shfl(acc2[4][r], (lane & 48));
#pragma unroll
    for (int c = 0; c < 4; ++c) {
      const float o = acc2[c][r] / den;
      avb[(grow0 + rbase + r) * 1024 + h * 64 + c * 16 + lr] = f2bf(o);
    }
  }
}

// ---------- launch ----------
extern "C" void kernel_launch(void* const* d_in, const int* in_sizes, int n_in,
                              void* d_out, int out_size, void* d_ws, size_t ws_size,
                              hipStream_t stream) {
  char* ws = (char*)d_ws;

  const size_t OFF_FLAG = 0;                       // 256
  const size_t OFF_WQKVT = 256;                    // 6,291,456
  const size_t OFF_WOT = OFF_WQKVT + 6291456;      // 2,097,152
  const size_t OFF_PROJC = OFF_WOT + 2097152;      // 32,768
  const size_t OFF_SINUC = OFF_PROJC + 32768;      // 524,288
  const size_t OFF_XH = OFF_SINUC + 524288;        // 16,777,216 (reused as av)
  const size_t OFF_XL = OFF_XH + 16777216;         // 16,777,216 (unused)
  const size_t OFF_QKF = OFF_XL + 16777216;        // 67,108,864 (8192x2048 fp32 rotated q,k)
  const size_t OFF_VB = OFF_QKF + 67108864;        // 16,777,216 (8192x1024 bf16 v)
  const size_t OFF_DIAGQ = OFF_VB + 16777216;      // 524,288
  const size_t OFF_DIAGK = OFF_DIAGQ + 524288;     // 524,288
  const size_t OFF_MK = OFF_DIAGK + 524288;        // 32,768
  const size_t OFF_KVS = OFF_MK + 32768;           // 2,621,440

  int* flag = (int*)(ws + OFF_FLAG);
  USHORT* wqkvt = (USHORT*)(ws + OFF_WQKVT);
  USHORT* wot = (USHORT*)(ws + OFF_WOT);
  USHORT* projc = (USHORT*)(ws + OFF_PROJC);
  USHORT* sinuc = (USHORT*)(ws + OFF_SINUC);
  USHORT* xh = (USHORT*)(ws + OFF_XH);
  USHORT* avb = (USHORT*)(ws + OFF_XH);  // alias: xh dead after gemm1
  float* qkf = (float*)(ws + OFF_QKF);
  USHORT* vb = (USHORT*)(ws + OFF_VB);
  float* diagq = (float*)(ws + OFF_DIAGQ);
  float* diagk = (float*)(ws + OFF_DIAGK);
  unsigned* mk = (unsigned*)(ws + OFF_MK);
  float* kvsb = (float*)(ws + OFF_KVS);

  hipMemsetAsync(ws + OFF_FLAG, 0, 256, stream);
  hipMemsetAsync(ws + OFF_MK, 0, 32768, stream);
  hipMemsetAsync(ws + OFF_KVS, 0, 2621440, stream);

  detect_kernel<<<1, 256, 0, stream>>>((const USHORT*)d_in[1], flag);
  cvt_x_kernel<<<4368, 256, 0, stream>>>(d_in[0], xh, d_in[5], d_in[6], projc, sinuc, flag);
  transpose_w_kernel<<<dim3(16, 16, 4), 256, 0, stream>>>(d_in[1], d_in[2], d_in[3], d_in[4],
                                                          wqkvt, wot, flag);
  // qkv = x @ [Wq|Wk|Wv]; rotary fused, q/k stored fp32, v stored bf16
  gemm_bt<true, false><<<dim3(24, 64), 256, 0, stream>>>(
      xh, wqkvt, qkf, vb, sinuc, diagq, diagk,
      8192, 3072, 1024, 1024, 1024, 2048, 1024, 2048, flag);
  ddk_max_kernel<<<dim3(64, 32), 256, 0, stream>>>(qkf, projc, mk);
  kvs_accum_kernel<<<dim3(8, 2, 32), 256, 0, stream>>>(qkf, vb, projc, diagk, mk, kvsb);
  qav_kernel<<<dim3(64, 32), 256, 0, stream>>>(qkf, projc, diagq, kvsb, avb);
  // out = av @ Wo  (output dtype per flag)
  gemm_bt<false, true><<<dim3(8, 64), 256, 0, stream>>>(
      avb, wot, d_out, nullptr, nullptr, nullptr, nullptr,
      8192, 1024, 1024, 1024, 1024, 1024, 0, 0, flag);
}

// Round 11
// 235.707 us; speedup vs baseline: 1.3448x; 1.0353x over previous
//
#include <hip/hip_runtime.h>

typedef __attribute__((ext_vector_type(8))) short short8;
typedef __attribute__((ext_vector_type(4))) float f32x4;
typedef unsigned short USHORT;

#define DNORM 0.35355339059327373f  // 64^-0.25
#define AS1(p) ((const __attribute__((address_space(1))) void*)(p))
#define AS3(p) ((__attribute__((address_space(3))) void*)(p))

// ---------- helpers ----------
__device__ __forceinline__ USHORT f2bf(float f) {
  union { float f; unsigned u; } v; v.f = f;
  unsigned r = v.u + 0x7fffu + ((v.u >> 16) & 1u);
  return (USHORT)(r >> 16);
}
__device__ __forceinline__ float bf2f(USHORT u) {
  union { unsigned u; float f; } v; v.u = ((unsigned)u) << 16;
  return v.f;
}
__device__ __forceinline__ unsigned fkey(float f) {
  union { float f; unsigned u; } v; v.f = f;
  return (v.u & 0x80000000u) ? ~v.u : (v.u | 0x80000000u);
}
__device__ __forceinline__ float keyf(unsigned k) {
  union { unsigned u; float f; } v;
  v.u = (k & 0x80000000u) ? (k ^ 0x80000000u) : ~k;
  return v.f;
}

// stage 16 fp32 -> hi/lo bf16 into swizzled LDS rows (shared by ddk/kvs/qav)
__device__ __forceinline__ void stage_hl16(const float* __restrict__ src,
                                           USHORT* __restrict__ Ah, USHORT* __restrict__ Al,
                                           int r, int kc) {
  float b[16];
  *(float4*)&b[0] = *(const float4*)(src);
  *(float4*)&b[4] = *(const float4*)(src + 4);
  *(float4*)&b[8] = *(const float4*)(src + 8);
  *(float4*)&b[12] = *(const float4*)(src + 12);
  const int swz = (r & 7) << 3;
  unsigned H[8], L[8];
#pragma unroll
  for (int p = 0; p < 8; ++p) {
    USHORT h0 = f2bf(b[2 * p]), h1 = f2bf(b[2 * p + 1]);
    USHORT l0 = f2bf(b[2 * p] - bf2f(h0)), l1 = f2bf(b[2 * p + 1] - bf2f(h1));
    H[p] = (unsigned)h0 | ((unsigned)h1 << 16);
    L[p] = (unsigned)l0 | ((unsigned)l1 << 16);
  }
  *(uint4*)&Ah[r * 64 + (kc ^ swz)] = make_uint4(H[0], H[1], H[2], H[3]);
  *(uint4*)&Ah[r * 64 + ((kc + 8) ^ swz)] = make_uint4(H[4], H[5], H[6], H[7]);
  *(uint4*)&Al[r * 64 + (kc ^ swz)] = make_uint4(L[0], L[1], L[2], L[3]);
  *(uint4*)&Al[r * 64 + ((kc + 8) ^ swz)] = make_uint4(L[4], L[5], L[6], L[7]);
}

// ---------- dtype detect: bf16-view of fp32 data has huge-exponent junk ----------
__global__ __launch_bounds__(256) void detect_kernel(const USHORT* __restrict__ w,
                                                     int* __restrict__ flag) {
  const int t = threadIdx.x;
  unsigned mx = 0;
#pragma unroll 8
  for (int c = 0; c < 64; ++c) {
    unsigned a = (unsigned)w[c * 256 + t] & 0x7FFFu;
    if (a > mx) mx = a;
  }
  if (mx > 0x4480u) atomicOr(flag, 1);
}

// ---------- x -> bf16; also proj+sinu convert ----------
__global__ __launch_bounds__(256) void cvt_x_kernel(const void* __restrict__ xin,
                                                    USHORT* __restrict__ xh,
                                                    const void* __restrict__ proj,
                                                    const void* __restrict__ sinu,
                                                    USHORT* __restrict__ projc,
                                                    USHORT* __restrict__ sinuc,
                                                    const int* __restrict__ flag) {
  if (blockIdx.x >= 4096) {  // proj+sinu tail
    const int i = ((blockIdx.x - 4096) * 256 + threadIdx.x) * 4;
    const int isp = (i < 16384);
    const int off = isp ? i : (i - 16384);
    const void* src = isp ? proj : sinu;
    USHORT* dst = isp ? projc : sinuc;
    if (*flag) {
      float4 v = *(const float4*)((const float*)src + off);
      USHORT a = f2bf(v.x), b = f2bf(v.y), c = f2bf(v.z), d = f2bf(v.w);
      *(uint2*)(dst + off) = make_uint2((unsigned)a | ((unsigned)b << 16),
                                        (unsigned)c | ((unsigned)d << 16));
    } else {
      *(uint2*)(dst + off) = *(const uint2*)((const USHORT*)src + off);
    }
    return;
  }
  const size_t i = ((size_t)blockIdx.x * 256 + threadIdx.x) * 8;
  if (*flag) {
    const float* xf = (const float*)xin;
    float4 a = *(const float4*)(xf + i);
    float4 b = *(const float4*)(xf + i + 4);
    float c[8] = {a.x, a.y, a.z, a.w, b.x, b.y, b.z, b.w};
    unsigned ho[4];
#pragma unroll
    for (int j = 0; j < 4; ++j) {
      USHORT h0 = f2bf(c[2 * j]), h1 = f2bf(c[2 * j + 1]);
      ho[j] = (unsigned)h0 | ((unsigned)h1 << 16);
    }
    *(uint4*)(xh + i) = make_uint4(ho[0], ho[1], ho[2], ho[3]);
  } else {
    uint4 u = *(const uint4*)((const USHORT*)xin + i);
    *(uint4*)(xh + i) = u;
  }
}

// ---------- transpose W (1024x1024 -> bf16 transposed), dtype-adaptive ----------
__global__ __launch_bounds__(256) void transpose_w_kernel(const void* __restrict__ Wq,
                                                          const void* __restrict__ Wk,
                                                          const void* __restrict__ Wv,
                                                          const void* __restrict__ Wo,
                                                          USHORT* __restrict__ wqkvt,
                                                          USHORT* __restrict__ wot,
                                                          const int* __restrict__ flag) {
  __shared__ __align__(16) USHORT tile[64][80];
  const int z = blockIdx.z;
  const void* src = (z == 0) ? Wq : (z == 1) ? Wk : (z == 2) ? Wv : Wo;
  USHORT* dst = (z < 3) ? (wqkvt + (size_t)z * 1048576) : wot;
  const int r0 = blockIdx.y * 64, c0 = blockIdx.x * 64;
  const int t = threadIdx.x;
  const int rr = t >> 2, c4 = (t & 3) * 16;
  if (*flag) {
    const float* s = (const float*)src + (size_t)(r0 + rr) * 1024 + c0 + c4;
#pragma unroll
    for (int i = 0; i < 4; ++i) {
      float4 v = *(const float4*)(s + i * 4);
      tile[rr][c4 + i * 4 + 0] = f2bf(v.x);
      tile[rr][c4 + i * 4 + 1] = f2bf(v.y);
      tile[rr][c4 + i * 4 + 2] = f2bf(v.z);
      tile[rr][c4 + i * 4 + 3] = f2bf(v.w);
    }
  } else {
    const USHORT* s = (const USHORT*)src + (size_t)(r0 + rr) * 1024 + c0 + c4;
    *(uint4*)&tile[rr][c4] = *(const uint4*)s;
    *(uint4*)&tile[rr][c4 + 8] = *(const uint4*)(s + 8);
  }
  __syncthreads();
  USHORT tmp[16];
#pragma unroll
  for (int i = 0; i < 16; ++i) tmp[i] = tile[c4 + i][rr];
  uint4 o0, o1;
  o0.x = (unsigned)tmp[0] | ((unsigned)tmp[1] << 16);
  o0.y = (unsigned)tmp[2] | ((unsigned)tmp[3] << 16);
  o0.z = (unsigned)tmp[4] | ((unsigned)tmp[5] << 16);
  o0.w = (unsigned)tmp[6] | ((unsigned)tmp[7] << 16);
  o1.x = (unsigned)tmp[8] | ((unsigned)tmp[9] << 16);
  o1.y = (unsigned)tmp[10] | ((unsigned)tmp[11] << 16);
  o1.z = (unsigned)tmp[12] | ((unsigned)tmp[13] << 16);
  o1.w = (unsigned)tmp[14] | ((unsigned)tmp[15] << 16);
  USHORT* d = dst + (size_t)(c0 + rr) * 1024 + r0 + c4;
  *(uint4*)d = o0;
  *(uint4*)(d + 8) = o1;
}

// ---------- GEMM: C(MxN) = A(MxK) @ Bt(NxK)^T, global_load_lds + XOR swizzle ----------
// XCD-aware bijective block swizzle (grid count % 8 == 0).
// ROTEPI: cols < NLO -> rotate fp32, store fp32 + diag; cols >= NLO -> bf16 to Vb.
// FLAGOUT: store fp32 when *flag else bf16 (gemm2).
template <bool ROTEPI, bool FLAGOUT>
__global__ __launch_bounds__(256) void gemm_bt(const USHORT* __restrict__ A,
                                               const USHORT* __restrict__ Bt,
                                               void* __restrict__ Cv,
                                               USHORT* __restrict__ Vb,
                                               const USHORT* __restrict__ sinu,
                                               float* __restrict__ diag_q,
                                               float* __restrict__ diag_k,
                                               int M, int N, int K, int lda, int ldb, int ldc,
                                               int ldv, int NLO, const int* __restrict__ flag) {
  __shared__ __align__(16) USHORT As[8192];   // [128][64] swizzled
  __shared__ __align__(16) USHORT Bs[8192];   // [128][64] swizzled
  const int fl = *flag;
  const int t = threadIdx.x;
  const int lane = t & 63, wave = t >> 6;
  const int lr = lane & 15, lg = lane >> 4;
  const int nwg = gridDim.x * gridDim.y;
  const int orig = blockIdx.y * gridDim.x + blockIdx.x;
  const int tile = (orig & 7) * (nwg >> 3) + (orig >> 3);
  const int bx = tile % gridDim.x, by = tile / gridDim.x;
  const int row0 = by * 128, col0 = bx * 128;
  const int wr = (wave >> 1) * 64, wc = (wave & 1) * 64;
  f32x4 acc[4][4] = {};
  for (int k0 = 0; k0 < K; k0 += 64) {
#pragma unroll
    for (int c = 0; c < 4; ++c) {
      const int e = c * 256 + t;
      const int r = e >> 3;                       // logical row 0..127
      const int ch = (t & 7) ^ (r & 7);           // inverse-swizzled source chunk
      const size_t goffA = (size_t)(row0 + r) * lda + k0 + ch * 8;
      const size_t goffB = (size_t)(col0 + r) * ldb + k0 + ch * 8;
      __builtin_amdgcn_global_load_lds(AS1(A + goffA), AS3(&As[c * 2048 + wave * 512]), 16, 0, 0);
      __builtin_amdgcn_global_load_lds(AS1(Bt + goffB), AS3(&Bs[c * 2048 + wave * 512]), 16, 0, 0);
    }
    __syncthreads();
#pragma unroll
    for (int ks = 0; ks < 2; ++ks) {
      const int koff = ks * 32 + (lg << 3);
      short8 av_[4], bv[4];
#pragma unroll
      for (int i = 0; i < 4; ++i) {
        const int ar = wr + i * 16 + lr;
        av_[i] = *(const short8*)&As[ar * 64 + (koff ^ ((ar & 7) << 3))];
      }
#pragma unroll
      for (int j = 0; j < 4; ++j) {
        const int br = wc + j * 16 + lr;
        bv[j] = *(const short8*)&Bs[br * 64 + (koff ^ ((br & 7) << 3))];
      }
#pragma unroll
      for (int i = 0; i < 4; ++i)
#pragma unroll
        for (int j = 0; j < 4; ++j)
          acc[i][j] = __builtin_amdgcn_mfma_f32_16x16x32_bf16(av_[i], bv[j], acc[i][j], 0, 0, 0);
    }
    __syncthreads();
  }
  if constexpr (ROTEPI) {
    if (col0 < NLO) {
      // q/k region: rotate fp32, store fp32, diag
      const int G0 = col0 + wc;          // wave's head base col (64-wide = 1 head)
      const int which = G0 >> 10;        // 0=q, 1=k
      const int h = (G0 & 1023) >> 6;
      float* qk = (float*)Cv;
#pragma unroll
      for (int i = 0; i < 4; ++i) {
        float ss[4] = {0.f, 0.f, 0.f, 0.f};
#pragma unroll
        for (int j = 0; j < 4; ++j) {
          const int G = G0 + j * 16 + lr;
          const int d = G & 63;
          const int j2 = d >> 1;
#pragma unroll
          for (int r = 0; r < 4; ++r) {
            const int R = row0 + wr + i * 16 + (lg << 2) + r;
            const int l = R & 4095;
            const float own = acc[i][j][r];
            const float oth = __shfl_xor(own, 1);
            const float s = bf2f(sinu[l * 64 + j2]);
            const float co = bf2f(sinu[l * 64 + 32 + j2]);
            const float ro = (d & 1) ? (own * co + oth * s) : (own * co - oth * s);
            ss[r] += ro * ro;
            qk[(size_t)R * ldc + G] = ro;
          }
        }
#pragma unroll
        for (int r = 0; r < 4; ++r) {
          float v_ = ss[r];
          v_ += __shfl_xor(v_, 1);
          v_ += __shfl_xor(v_, 2);
          v_ += __shfl_xor(v_, 4);
          v_ += __shfl_xor(v_, 8);
          if (lr == 0) {
            const int R = row0 + wr + i * 16 + (lg << 2) + r;
            (which ? diag_k : diag_q)[R * 16 + h] = v_ * 0.0625f;  // 0.5*DNORM^2
          }
        }
      }
    } else {
      // V region: bf16 store to compact v buffer
#pragma unroll
      for (int i = 0; i < 4; ++i) {
#pragma unroll
        for (int r = 0; r < 4; ++r) {
          const int row = row0 + wr + i * 16 + (lg << 2) + r;
#pragma unroll
          for (int j = 0; j < 4; ++j) {
            const int col = col0 + wc + j * 16 + lr - NLO;
            Vb[(size_t)row * ldv + col] = f2bf(acc[i][j][r]);
          }
        }
      }
    }
    return;
  }
#pragma unroll
  for (int i = 0; i < 4; ++i) {
#pragma unroll
    for (int r = 0; r < 4; ++r) {
      const int row = row0 + wr + i * 16 + (lg << 2) + r;
#pragma unroll
      for (int j = 0; j < 4; ++j) {
        const int col = col0 + wc + j * 16 + lr;
        const float v = acc[i][j][r];
        if constexpr (FLAGOUT) {
          if (fl) ((float*)Cv)[(size_t)row * ldc + col] = v;
          else ((USHORT*)Cv)[(size_t)row * ldc + col] = f2bf(v);
        } else {
          ((USHORT*)Cv)[(size_t)row * ldc + col] = f2bf(v);
        }
      }
    }
  }
}

// ---------- ddk max over (h, m) per (b, l): atomicMax into mk[row] ----------
__global__ __launch_bounds__(256) void ddk_max_kernel(const float* __restrict__ qkf,
                                                      const USHORT* __restrict__ proj,
                                                      unsigned* __restrict__ mk) {
  __shared__ __align__(16) USHORT Ph[16384];
  __shared__ __align__(16) USHORT Ah[4096], Al[4096];
  const int t = threadIdx.x, lane = t & 63, wave = t >> 6;
  const int lr = lane & 15, lg = lane >> 4;
  const int bh = blockIdx.y, b = bh >> 4, h = bh & 15;
  const size_t grow0 = (size_t)b * 4096 + blockIdx.x * 64;
  {
#pragma unroll
    for (int c = 0; c < 8; ++c)
      *(uint4*)&Ph[t * 64 + ((c ^ (t & 7)) << 3)] = *(const uint4*)(proj + t * 64 + c * 8);
  }
  {
    const int r = t >> 2, kc = (t & 3) * 16;
    stage_hl16(qkf + (grow0 + r) * 2048 + 1024 + h * 64 + kc, Ah, Al, r, kc);
  }
  __syncthreads();
  f32x4 acc[16] = {};
#pragma unroll
  for (int ks = 0; ks < 2; ++ks) {
    const int koff = ks * 32 + (lg << 3);
    const int ar = wave * 16 + lr;
    short8 a_h = *(const short8*)&Ah[ar * 64 + (koff ^ ((ar & 7) << 3))];
    short8 a_l = *(const short8*)&Al[ar * 64 + (koff ^ ((ar & 7) << 3))];
#pragma unroll
    for (int n = 0; n < 16; ++n) {
      const int br = n * 16 + lr;
      short8 b_h = *(const short8*)&Ph[br * 64 + (koff ^ ((br & 7) << 3))];
      acc[n] = __builtin_amdgcn_mfma_f32_16x16x32_bf16(a_h, b_h, acc[n], 0, 0, 0);
      acc[n] = __builtin_amdgcn_mfma_f32_16x16x32_bf16(a_l, b_h, acc[n], 0, 0, 0);
    }
  }
#pragma unroll
  for (int r = 0; r < 4; ++r) {
    float m_ = acc[0][r];
#pragma unroll
    for (int n = 1; n < 16; ++n) m_ = fmaxf(m_, acc[n][r]);
    m_ = fmaxf(m_, __shfl_xor(m_, 1));
    m_ = fmaxf(m_, __shfl_xor(m_, 2));
    m_ = fmaxf(m_, __shfl_xor(m_, 4));
    m_ = fmaxf(m_, __shfl_xor(m_, 8));
    if (lr == 0) {
      const int row = (int)grow0 + wave * 16 + (lg << 2) + r;
      atomicMax(&mk[row], fkey(m_ * DNORM));
    }
  }
}

// ---------- kp = exp(ddk*DN - diag - mk) + EPS; kvs_ext += kp^T @ [v | 1] ----------
__global__ __launch_bounds__(256) void kvs_accum_kernel(const float* __restrict__ qkf,
                                                        const USHORT* __restrict__ vb,
                                                        const USHORT* __restrict__ proj,
                                                        const float* __restrict__ diag_k,
                                                        const unsigned* __restrict__ mk,
                                                        float* __restrict__ kvs_ext) {
  __shared__ __align__(16) USHORT Ph[8192];    // [128][64]
  __shared__ __align__(16) USHORT Ah[4096], Al[4096];
  __shared__ __align__(16) USHORT KpT[8192];   // [128][64]
  __shared__ __align__(16) USHORT Vt[5120];    // [80][64]
  const int t = threadIdx.x, lane = t & 63, wave = t >> 6;
  const int lr = lane & 15, lg = lane >> 4;
  const int bh = blockIdx.z, b = bh >> 4, h = bh & 15;
  const int fh = blockIdx.y;
  const int lstart = blockIdx.x * 512;
  {
    const int pr = t >> 1;
    const USHORT* src = proj + (size_t)(fh * 128 + pr) * 64;
#pragma unroll
    for (int c = 0; c < 4; ++c) {
      const int ch = (t & 1) * 4 + c;
      *(uint4*)&Ph[pr * 64 + ((ch ^ (pr & 7)) << 3)] = *(const uint4*)(src + ch * 8);
    }
  }
  if (t < 64) {
#pragma unroll
    for (int r = 64; r < 80; ++r) Vt[r * 64 + t] = (r == 64) ? (USHORT)0x3F80 : (USHORT)0;
  }
  f32x4 acc2[2][5] = {};
  for (int sub = 0; sub < 8; ++sub) {
    const int row0 = lstart + sub * 64;
    const size_t grow0 = (size_t)b * 4096 + row0;
    {
      const int r = t >> 2, kc = (t & 3) * 16;
      stage_hl16(qkf + (grow0 + r) * 2048 + 1024 + h * 64 + kc, Ah, Al, r, kc);
    }
    {
      const int rv = t & 63, dc = (t >> 6) * 16;
      const USHORT* sv = vb + (grow0 + rv) * 1024 + h * 64 + dc;
      uint4 u0 = *(const uint4*)sv;
      uint4 u1 = *(const uint4*)(sv + 8);
      unsigned wsrc[8] = {u0.x, u0.y, u0.z, u0.w, u1.x, u1.y, u1.z, u1.w};
#pragma unroll
      for (int i = 0; i < 8; ++i) {
        const int d0 = dc + 2 * i;
        Vt[d0 * 64 + (rv ^ ((d0 & 7) << 3))] = (USHORT)(wsrc[i] & 0xffff);
        Vt[(d0 + 1) * 64 + (rv ^ (((d0 + 1) & 7) << 3))] = (USHORT)(wsrc[i] >> 16);
      }
    }
    __syncthreads();
    f32x4 acc1[8] = {};
#pragma unroll
    for (int ks = 0; ks < 2; ++ks) {
      const int koff = ks * 32 + (lg << 3);
      const int ar = wave * 16 + lr;
      short8 a_h = *(const short8*)&Ah[ar * 64 + (koff ^ ((ar & 7) << 3))];
      short8 a_l = *(const short8*)&Al[ar * 64 + (koff ^ ((ar & 7) << 3))];
#pragma unroll
      for (int n = 0; n < 8; ++n) {
        const int br = n * 16 + lr;
        short8 b_h = *(const short8*)&Ph[br * 64 + (koff ^ ((br & 7) << 3))];
        acc1[n] = __builtin_amdgcn_mfma_f32_16x16x32_bf16(a_h, b_h, acc1[n], 0, 0, 0);
        acc1[n] = __builtin_amdgcn_mfma_f32_16x16x32_bf16(a_l, b_h, acc1[n], 0, 0, 0);
      }
    }
    const int rbase = wave * 16 + (lg << 2);
    float dg[4], mkr[4];
#pragma unroll
    for (int r = 0; r < 4; ++r) {
      dg[r] = diag_k[(grow0 + rbase + r) * 16 + h];
      mkr[r] = keyf(mk[grow0 + rbase + r]);
    }
#pragma unroll
    for (int n = 0; n < 8; ++n) {
      const int col = n * 16 + lr;
      USHORT pk[4];
#pragma unroll
      for (int r = 0; r < 4; ++r)
        pk[r] = f2bf(__expf(acc1[n][r] * DNORM - dg[r] - mkr[r]) + 1e-6f);
      const unsigned w0 = (unsigned)pk[0] | ((unsigned)pk[1] << 16);
      const unsigned w1 = (unsigned)pk[2] | ((unsigned)pk[3] << 16);
      *(uint2*)&KpT[col * 64 + (rbase ^ ((col & 7) << 3))] = make_uint2(w0, w1);
    }
    __syncthreads();
#pragma unroll
    for (int ks = 0; ks < 2; ++ks) {
      const int koff = ks * 32 + (lg << 3);
      short8 af[2];
#pragma unroll
      for (int i = 0; i < 2; ++i) {
        const int m = wave * 32 + i * 16 + lr;
        af[i] = *(const short8*)&KpT[m * 64 + (koff ^ ((m & 7) << 3))];
      }
#pragma unroll
      for (int c = 0; c < 5; ++c) {
        const int d = c * 16 + lr;
        short8 bv = *(const short8*)&Vt[d * 64 + (koff ^ ((d & 7) << 3))];
#pragma unroll
        for (int i = 0; i < 2; ++i)
          acc2[i][c] = __builtin_amdgcn_mfma_f32_16x16x32_bf16(af[i], bv, acc2[i][c], 0, 0, 0);
      }
    }
    __syncthreads();
  }
  float* basep = kvs_ext + (size_t)bh * 20480 + (size_t)fh * 128 * 80;
#pragma unroll
  for (int i = 0; i < 2; ++i) {
    const int mrow = wave * 32 + i * 16 + (lg << 2);
#pragma unroll
    for (int c = 0; c < 5; ++c) {
      const int col = c * 16 + lr;
      if (c == 4 && lr != 0) continue;
#pragma unroll
      for (int r = 0; r < 4; ++r)
        atomicAdd(basep + (size_t)(mrow + r) * 80 + col, acc2[i][c][r]);
    }
  }
}

// ---------- kvs fp32 [bh][m][d] -> bf16 transposed [bh][d][m] ----------
__global__ __launch_bounds__(256) void cvt_kvs_kernel(const float* __restrict__ kvs_ext,
                                                      USHORT* __restrict__ kvsT16) {
  const int bh = blockIdx.x;
  const float* src = kvs_ext + (size_t)bh * 20480;
  USHORT* dst = kvsT16 + (size_t)bh * 20480;
  const int m = threadIdx.x;
#pragma unroll 8
  for (int d = 0; d < 80; ++d)
    dst[d * 256 + m] = f2bf(src[m * 80 + d]);
}

// ---------- qp = exp(ddq*DN - diag - rowmax)+EPS; av = (qp@[kvs|ks])/den ----------
__global__ __launch_bounds__(256) void qav_kernel(const float* __restrict__ qkf,
                                                  const USHORT* __restrict__ proj,
                                                  const float* __restrict__ diag_q,
                                                  const USHORT* __restrict__ kvsT16,
                                                  USHORT* __restrict__ avb) {
  __shared__ __align__(16) USHORT smem[36864];
  USHORT* Ph = smem;            // [256][64] swz
  USHORT* Qp = smem;            // [64][256] swz (aliases Ph)
  USHORT* Ah = smem + 16384;    // [64][64]
  USHORT* Al = smem + 20480;    // [64][64]
  USHORT* Btl = smem + 16384;   // [80][256] swz (aliases Ah/Al)
  const int t = threadIdx.x, lane = t & 63, wave = t >> 6;
  const int lr = lane & 15, lg = lane >> 4;
  const int bh = blockIdx.y, b = bh >> 4, h = bh & 15;
  const size_t grow0 = (size_t)b * 4096 + blockIdx.x * 64;
  {
#pragma unroll
    for (int c = 0; c < 8; ++c)
      *(uint4*)&Ph[t * 64 + ((c ^ (t & 7)) << 3)] = *(const uint4*)(proj + t * 64 + c * 8);
  }
  {
    const int r = t >> 2, kc = (t & 3) * 16;
    stage_hl16(qkf + (grow0 + r) * 2048 + h * 64 + kc, Ah, Al, r, kc);
  }
  __syncthreads();
  f32x4 acc1[16] = {};
#pragma unroll
  for (int ks = 0; ks < 2; ++ks) {
    const int koff = ks * 32 + (lg << 3);
    const int ar = wave * 16 + lr;
    short8 a_h = *(const short8*)&Ah[ar * 64 + (koff ^ ((ar & 7) << 3))];
    short8 a_l = *(const short8*)&Al[ar * 64 + (koff ^ ((ar & 7) << 3))];
#pragma unroll
    for (int n = 0; n < 16; ++n) {
      const int br = n * 16 + lr;
      short8 b_h = *(const short8*)&Ph[br * 64 + (koff ^ ((br & 7) << 3))];
      acc1[n] = __builtin_amdgcn_mfma_f32_16x16x32_bf16(a_h, b_h, acc1[n], 0, 0, 0);
      acc1[n] = __builtin_amdgcn_mfma_f32_16x16x32_bf16(a_l, b_h, acc1[n], 0, 0, 0);
    }
  }
  __syncthreads();  // Ph/Ah/Al now dead; safe to overlay Qp/Btl
  {
    const USHORT* src = kvsT16 + (size_t)bh * 20480;
#pragma unroll
    for (int c = 0; c < 10; ++c) {
      const int e = c * 256 + t;        // 8-short chunk id, 0..2559
      const int d = e >> 5, ch = e & 31;
      *(uint4*)&Btl[d * 256 + ((ch ^ (d & 7)) << 3)] = *(const uint4*)(src + d * 256 + ch * 8);
    }
  }
  const int rbase = wave * 16 + (lg << 2);
  float dg[4], mx[4];
#pragma unroll
  for (int r = 0; r < 4; ++r) dg[r] = diag_q[(grow0 + rbase + r) * 16 + h];
#pragma unroll
  for (int r = 0; r < 4; ++r) {
    float m_ = acc1[0][r];
#pragma unroll
    for (int n = 1; n < 16; ++n) m_ = fmaxf(m_, acc1[n][r]);
    m_ = fmaxf(m_, __shfl_xor(m_, 1));
    m_ = fmaxf(m_, __shfl_xor(m_, 2));
    m_ = fmaxf(m_, __shfl_xor(m_, 4));
    m_ = fmaxf(m_, __shfl_xor(m_, 8));
    mx[r] = m_ * DNORM;
  }
#pragma unroll
  for (int n = 0; n < 16; ++n) {
    const int col = n * 16 + lr;
#pragma unroll
    for (int r = 0; r < 4; ++r) {
      const int row = rbase + r;
      Qp[row * 256 + (col ^ ((row & 7) << 3))] =
          f2bf(__expf(acc1[n][r] * DNORM - dg[r] - mx[r]) + 1e-6f);
    }
  }
  __syncthreads();
  f32x4 acc2[5] = {};
#pragma unroll
  for (int ks2 = 0; ks2 < 8; ++ks2) {
    const int koff = ks2 * 32 + (lg << 3);
    const int ar = wave * 16 + lr;
    short8 a = *(const short8*)&Qp[ar * 256 + (koff ^ ((ar & 7) << 3))];
#pragma unroll
    for (int c = 0; c < 5; ++c) {
      const int cr = c * 16 + lr;
      short8 bv = *(const short8*)&Btl[cr * 256 + (koff ^ ((cr & 7) << 3))];
      acc2[c] = __builtin_amdgcn_mfma_f32_16x16x32_bf16(a, bv, acc2[c], 0, 0, 0);
    }
  }
#pragma unroll
  for (int r = 0; r < 4; ++r) {
    const float den = __shfl(acc2[4][r], (lane & 48));
#pragma unroll
    for (int c = 0; c < 4; ++c) {
      const float o = acc2[c][r] / den;
      avb[(grow0 + rbase + r) * 1024 + h * 64 + c * 16 + lr] = f2bf(o);
    }
  }
}

// ---------- launch ----------
extern "C" void kernel_launch(void* const* d_in, const int* in_sizes, int n_in,
                              void* d_out, int out_size, void* d_ws, size_t ws_size,
                              hipStream_t stream) {
  char* ws = (char*)d_ws;

  const size_t OFF_FLAG = 0;                       // 256
  const size_t OFF_WQKVT = 256;                    // 6,291,456
  const size_t OFF_WOT = OFF_WQKVT + 6291456;      // 2,097,152
  const size_t OFF_PROJC = OFF_WOT + 2097152;      // 32,768
  const size_t OFF_SINUC = OFF_PROJC + 32768;      // 524,288
  const size_t OFF_XH = OFF_SINUC + 524288;        // 16,777,216 (reused as av)
  const size_t OFF_XL = OFF_XH + 16777216;         // 16,777,216 (unused)
  const size_t OFF_QKF = OFF_XL + 16777216;        // 67,108,864 (8192x2048 fp32 rotated q,k)
  const size_t OFF_VB = OFF_QKF + 67108864;        // 16,777,216 (8192x1024 bf16 v)
  const size_t OFF_DIAGQ = OFF_VB + 16777216;      // 524,288
  const size_t OFF_DIAGK = OFF_DIAGQ + 524288;     // 524,288
  const size_t OFF_MK = OFF_DIAGK + 524288;        // 32,768
  const size_t OFF_KVS = OFF_MK + 32768;           // 2,621,440
  const size_t OFF_KVST = OFF_KVS + 2621440;       // 1,310,720

  int* flag = (int*)(ws + OFF_FLAG);
  USHORT* wqkvt = (USHORT*)(ws + OFF_WQKVT);
  USHORT* wot = (USHORT*)(ws + OFF_WOT);
  USHORT* projc = (USHORT*)(ws + OFF_PROJC);
  USHORT* sinuc = (USHORT*)(ws + OFF_SINUC);
  USHORT* xh = (USHORT*)(ws + OFF_XH);
  USHORT* avb = (USHORT*)(ws + OFF_XH);  // alias: xh dead after gemm1
  float* qkf = (float*)(ws + OFF_QKF);
  USHORT* vb = (USHORT*)(ws + OFF_VB);
  float* diagq = (float*)(ws + OFF_DIAGQ);
  float* diagk = (float*)(ws + OFF_DIAGK);
  unsigned* mk = (unsigned*)(ws + OFF_MK);
  float* kvsb = (float*)(ws + OFF_KVS);
  USHORT* kvst = (USHORT*)(ws + OFF_KVST);

  hipMemsetAsync(ws + OFF_FLAG, 0, 256, stream);
  hipMemsetAsync(ws + OFF_MK, 0, 32768, stream);
  hipMemsetAsync(ws + OFF_KVS, 0, 2621440, stream);

  detect_kernel<<<1, 256, 0, stream>>>((const USHORT*)d_in[1], flag);
  cvt_x_kernel<<<4368, 256, 0, stream>>>(d_in[0], xh, d_in[5], d_in[6], projc, sinuc, flag);
  transpose_w_kernel<<<dim3(16, 16, 4), 256, 0, stream>>>(d_in[1], d_in[2], d_in[3], d_in[4],
                                                          wqkvt, wot, flag);
  // qkv = x @ [Wq|Wk|Wv]; rotary fused, q/k stored fp32, v stored bf16
  gemm_bt<true, false><<<dim3(24, 64), 256, 0, stream>>>(
      xh, wqkvt, qkf, vb, sinuc, diagq, diagk,
      8192, 3072, 1024, 1024, 1024, 2048, 1024, 2048, flag);
  ddk_max_kernel<<<dim3(64, 32), 256, 0, stream>>>(qkf, projc, mk);
  kvs_accum_kernel<<<dim3(8, 2, 32), 256, 0, stream>>>(qkf, vb, projc, diagk, mk, kvsb);
  cvt_kvs_kernel<<<32, 256, 0, stream>>>(kvsb, kvst);
  qav_kernel<<<dim3(64, 32), 256, 0, stream>>>(qkf, projc, diagq, kvst, avb);
  // out = av @ Wo  (output dtype per flag)
  gemm_bt<false, true><<<dim3(8, 64), 256, 0, stream>>>(
      avb, wot, d_out, nullptr, nullptr, nullptr, nullptr,
      8192, 1024, 1024, 1024, 1024, 1024, 0, 0, flag);
}

// Round 12
// 224.298 us; speedup vs baseline: 1.4132x; 1.0509x over previous
//
#include <hip/hip_runtime.h>

typedef __attribute__((ext_vector_type(8))) short short8;
typedef __attribute__((ext_vector_type(4))) float f32x4;
typedef unsigned short USHORT;

#define DNORM 0.35355339059327373f  // 64^-0.25
#define AS1(p) ((const __attribute__((address_space(1))) void*)(p))
#define AS3(p) ((__attribute__((address_space(3))) void*)(p))

// ---------- helpers ----------
__device__ __forceinline__ USHORT f2bf(float f) {
  union { float f; unsigned u; } v; v.f = f;
  unsigned r = v.u + 0x7fffu + ((v.u >> 16) & 1u);
  return (USHORT)(r >> 16);
}
__device__ __forceinline__ float bf2f(USHORT u) {
  union { unsigned u; float f; } v; v.u = ((unsigned)u) << 16;
  return v.f;
}
__device__ __forceinline__ unsigned fkey(float f) {
  union { float f; unsigned u; } v; v.f = f;
  return (v.u & 0x80000000u) ? ~v.u : (v.u | 0x80000000u);
}
__device__ __forceinline__ float keyf(unsigned k) {
  union { unsigned u; float f; } v;
  v.u = (k & 0x80000000u) ? (k ^ 0x80000000u) : ~k;
  return v.f;
}

// stage 16 fp32 -> hi/lo bf16 into swizzled LDS rows (shared by ddk/kvs/qav)
__device__ __forceinline__ void stage_hl16(const float* __restrict__ src,
                                           USHORT* __restrict__ Ah, USHORT* __restrict__ Al,
                                           int r, int kc) {
  float b[16];
  *(float4*)&b[0] = *(const float4*)(src);
  *(float4*)&b[4] = *(const float4*)(src + 4);
  *(float4*)&b[8] = *(const float4*)(src + 8);
  *(float4*)&b[12] = *(const float4*)(src + 12);
  const int swz = (r & 7) << 3;
  unsigned H[8], L[8];
#pragma unroll
  for (int p = 0; p < 8; ++p) {
    USHORT h0 = f2bf(b[2 * p]), h1 = f2bf(b[2 * p + 1]);
    USHORT l0 = f2bf(b[2 * p] - bf2f(h0)), l1 = f2bf(b[2 * p + 1] - bf2f(h1));
    H[p] = (unsigned)h0 | ((unsigned)h1 << 16);
    L[p] = (unsigned)l0 | ((unsigned)l1 << 16);
  }
  *(uint4*)&Ah[r * 64 + (kc ^ swz)] = make_uint4(H[0], H[1], H[2], H[3]);
  *(uint4*)&Ah[r * 64 + ((kc + 8) ^ swz)] = make_uint4(H[4], H[5], H[6], H[7]);
  *(uint4*)&Al[r * 64 + (kc ^ swz)] = make_uint4(L[0], L[1], L[2], L[3]);
  *(uint4*)&Al[r * 64 + ((kc + 8) ^ swz)] = make_uint4(L[4], L[5], L[6], L[7]);
}

// ---------- dtype detect: bf16-view of fp32 data has huge-exponent junk ----------
__global__ __launch_bounds__(256) void detect_kernel(const USHORT* __restrict__ w,
                                                     int* __restrict__ flag) {
  const int t = threadIdx.x;
  unsigned mx = 0;
#pragma unroll 8
  for (int c = 0; c < 64; ++c) {
    unsigned a = (unsigned)w[c * 256 + t] & 0x7FFFu;
    if (a > mx) mx = a;
  }
  if (mx > 0x4480u) atomicOr(flag, 1);
}

// ---------- x -> bf16; also proj+sinu convert ----------
__global__ __launch_bounds__(256) void cvt_x_kernel(const void* __restrict__ xin,
                                                    USHORT* __restrict__ xh,
                                                    const void* __restrict__ proj,
                                                    const void* __restrict__ sinu,
                                                    USHORT* __restrict__ projc,
                                                    USHORT* __restrict__ sinuc,
                                                    const int* __restrict__ flag) {
  if (blockIdx.x >= 4096) {  // proj+sinu tail
    const int i = ((blockIdx.x - 4096) * 256 + threadIdx.x) * 4;
    const int isp = (i < 16384);
    const int off = isp ? i : (i - 16384);
    const void* src = isp ? proj : sinu;
    USHORT* dst = isp ? projc : sinuc;
    if (*flag) {
      float4 v = *(const float4*)((const float*)src + off);
      USHORT a = f2bf(v.x), b = f2bf(v.y), c = f2bf(v.z), d = f2bf(v.w);
      *(uint2*)(dst + off) = make_uint2((unsigned)a | ((unsigned)b << 16),
                                        (unsigned)c | ((unsigned)d << 16));
    } else {
      *(uint2*)(dst + off) = *(const uint2*)((const USHORT*)src + off);
    }
    return;
  }
  const size_t i = ((size_t)blockIdx.x * 256 + threadIdx.x) * 8;
  if (*flag) {
    const float* xf = (const float*)xin;
    float4 a = *(const float4*)(xf + i);
    float4 b = *(const float4*)(xf + i + 4);
    float c[8] = {a.x, a.y, a.z, a.w, b.x, b.y, b.z, b.w};
    unsigned ho[4];
#pragma unroll
    for (int j = 0; j < 4; ++j) {
      USHORT h0 = f2bf(c[2 * j]), h1 = f2bf(c[2 * j + 1]);
      ho[j] = (unsigned)h0 | ((unsigned)h1 << 16);
    }
    *(uint4*)(xh + i) = make_uint4(ho[0], ho[1], ho[2], ho[3]);
  } else {
    uint4 u = *(const uint4*)((const USHORT*)xin + i);
    *(uint4*)(xh + i) = u;
  }
}

// ---------- transpose W (1024x1024 -> bf16 transposed), dtype-adaptive ----------
__global__ __launch_bounds__(256) void transpose_w_kernel(const void* __restrict__ Wq,
                                                          const void* __restrict__ Wk,
                                                          const void* __restrict__ Wv,
                                                          const void* __restrict__ Wo,
                                                          USHORT* __restrict__ wqkvt,
                                                          USHORT* __restrict__ wot,
                                                          const int* __restrict__ flag) {
  __shared__ __align__(16) USHORT tile[64][80];
  const int z = blockIdx.z;
  const void* src = (z == 0) ? Wq : (z == 1) ? Wk : (z == 2) ? Wv : Wo;
  USHORT* dst = (z < 3) ? (wqkvt + (size_t)z * 1048576) : wot;
  const int r0 = blockIdx.y * 64, c0 = blockIdx.x * 64;
  const int t = threadIdx.x;
  const int rr = t >> 2, c4 = (t & 3) * 16;
  if (*flag) {
    const float* s = (const float*)src + (size_t)(r0 + rr) * 1024 + c0 + c4;
#pragma unroll
    for (int i = 0; i < 4; ++i) {
      float4 v = *(const float4*)(s + i * 4);
      tile[rr][c4 + i * 4 + 0] = f2bf(v.x);
      tile[rr][c4 + i * 4 + 1] = f2bf(v.y);
      tile[rr][c4 + i * 4 + 2] = f2bf(v.z);
      tile[rr][c4 + i * 4 + 3] = f2bf(v.w);
    }
  } else {
    const USHORT* s = (const USHORT*)src + (size_t)(r0 + rr) * 1024 + c0 + c4;
    *(uint4*)&tile[rr][c4] = *(const uint4*)s;
    *(uint4*)&tile[rr][c4 + 8] = *(const uint4*)(s + 8);
  }
  __syncthreads();
  USHORT tmp[16];
#pragma unroll
  for (int i = 0; i < 16; ++i) tmp[i] = tile[c4 + i][rr];
  uint4 o0, o1;
  o0.x = (unsigned)tmp[0] | ((unsigned)tmp[1] << 16);
  o0.y = (unsigned)tmp[2] | ((unsigned)tmp[3] << 16);
  o0.z = (unsigned)tmp[4] | ((unsigned)tmp[5] << 16);
  o0.w = (unsigned)tmp[6] | ((unsigned)tmp[7] << 16);
  o1.x = (unsigned)tmp[8] | ((unsigned)tmp[9] << 16);
  o1.y = (unsigned)tmp[10] | ((unsigned)tmp[11] << 16);
  o1.z = (unsigned)tmp[12] | ((unsigned)tmp[13] << 16);
  o1.w = (unsigned)tmp[14] | ((unsigned)tmp[15] << 16);
  USHORT* d = dst + (size_t)(c0 + rr) * 1024 + r0 + c4;
  *(uint4*)d = o0;
  *(uint4*)(d + 8) = o1;
}

// ---------- GEMM: C(MxN) = A(MxK) @ Bt(NxK)^T, global_load_lds + XOR swizzle ----------
// XCD-aware bijective block swizzle (grid count % 8 == 0).
// __launch_bounds__(256,3): cap regalloc at 3 waves/SIMD (160 regs used <= 170 budget)
// ROTEPI: cols < NLO -> rotate fp32, store fp32 + diag; cols >= NLO -> bf16 to Vb.
// FLAGOUT: store fp32 when *flag else bf16 (gemm2).
template <bool ROTEPI, bool FLAGOUT>
__global__ __launch_bounds__(256, 3) void gemm_bt(const USHORT* __restrict__ A,
                                                  const USHORT* __restrict__ Bt,
                                                  void* __restrict__ Cv,
                                                  USHORT* __restrict__ Vb,
                                                  const USHORT* __restrict__ sinu,
                                                  float* __restrict__ diag_q,
                                                  float* __restrict__ diag_k,
                                                  int M, int N, int K, int lda, int ldb, int ldc,
                                                  int ldv, int NLO, const int* __restrict__ flag) {
  __shared__ __align__(16) USHORT As[8192];   // [128][64] swizzled
  __shared__ __align__(16) USHORT Bs[8192];   // [128][64] swizzled
  const int fl = *flag;
  const int t = threadIdx.x;
  const int lane = t & 63, wave = t >> 6;
  const int lr = lane & 15, lg = lane >> 4;
  const int nwg = gridDim.x * gridDim.y;
  const int orig = blockIdx.y * gridDim.x + blockIdx.x;
  const int tile = (orig & 7) * (nwg >> 3) + (orig >> 3);
  const int bx = tile % gridDim.x, by = tile / gridDim.x;
  const int row0 = by * 128, col0 = bx * 128;
  const int wr = (wave >> 1) * 64, wc = (wave & 1) * 64;
  f32x4 acc[4][4] = {};
  for (int k0 = 0; k0 < K; k0 += 64) {
#pragma unroll
    for (int c = 0; c < 4; ++c) {
      const int e = c * 256 + t;
      const int r = e >> 3;                       // logical row 0..127
      const int ch = (t & 7) ^ (r & 7);           // inverse-swizzled source chunk
      const size_t goffA = (size_t)(row0 + r) * lda + k0 + ch * 8;
      const size_t goffB = (size_t)(col0 + r) * ldb + k0 + ch * 8;
      __builtin_amdgcn_global_load_lds(AS1(A + goffA), AS3(&As[c * 2048 + wave * 512]), 16, 0, 0);
      __builtin_amdgcn_global_load_lds(AS1(Bt + goffB), AS3(&Bs[c * 2048 + wave * 512]), 16, 0, 0);
    }
    __syncthreads();
#pragma unroll
    for (int ks = 0; ks < 2; ++ks) {
      const int koff = ks * 32 + (lg << 3);
      short8 av_[4], bv[4];
#pragma unroll
      for (int i = 0; i < 4; ++i) {
        const int ar = wr + i * 16 + lr;
        av_[i] = *(const short8*)&As[ar * 64 + (koff ^ ((ar & 7) << 3))];
      }
#pragma unroll
      for (int j = 0; j < 4; ++j) {
        const int br = wc + j * 16 + lr;
        bv[j] = *(const short8*)&Bs[br * 64 + (koff ^ ((br & 7) << 3))];
      }
#pragma unroll
      for (int i = 0; i < 4; ++i)
#pragma unroll
        for (int j = 0; j < 4; ++j)
          acc[i][j] = __builtin_amdgcn_mfma_f32_16x16x32_bf16(av_[i], bv[j], acc[i][j], 0, 0, 0);
    }
    __syncthreads();
  }
  if constexpr (ROTEPI) {
    if (col0 < NLO) {
      // q/k region: rotate fp32, store fp32, diag
      const int G0 = col0 + wc;          // wave's head base col (64-wide = 1 head)
      const int which = G0 >> 10;        // 0=q, 1=k
      const int h = (G0 & 1023) >> 6;
      float* qk = (float*)Cv;
#pragma unroll
      for (int i = 0; i < 4; ++i) {
        float ss[4] = {0.f, 0.f, 0.f, 0.f};
#pragma unroll
        for (int j = 0; j < 4; ++j) {
          const int G = G0 + j * 16 + lr;
          const int d = G & 63;
          const int j2 = d >> 1;
#pragma unroll
          for (int r = 0; r < 4; ++r) {
            const int R = row0 + wr + i * 16 + (lg << 2) + r;
            const int l = R & 4095;
            const float own = acc[i][j][r];
            const float oth = __shfl_xor(own, 1);
            const float s = bf2f(sinu[l * 64 + j2]);
            const float co = bf2f(sinu[l * 64 + 32 + j2]);
            const float ro = (d & 1) ? (own * co + oth * s) : (own * co - oth * s);
            ss[r] += ro * ro;
            qk[(size_t)R * ldc + G] = ro;
          }
        }
#pragma unroll
        for (int r = 0; r < 4; ++r) {
          float v_ = ss[r];
          v_ += __shfl_xor(v_, 1);
          v_ += __shfl_xor(v_, 2);
          v_ += __shfl_xor(v_, 4);
          v_ += __shfl_xor(v_, 8);
          if (lr == 0) {
            const int R = row0 + wr + i * 16 + (lg << 2) + r;
            (which ? diag_k : diag_q)[R * 16 + h] = v_ * 0.0625f;  // 0.5*DNORM^2
          }
        }
      }
    } else {
      // V region: bf16 store to compact v buffer
#pragma unroll
      for (int i = 0; i < 4; ++i) {
#pragma unroll
        for (int r = 0; r < 4; ++r) {
          const int row = row0 + wr + i * 16 + (lg << 2) + r;
#pragma unroll
          for (int j = 0; j < 4; ++j) {
            const int col = col0 + wc + j * 16 + lr - NLO;
            Vb[(size_t)row * ldv + col] = f2bf(acc[i][j][r]);
          }
        }
      }
    }
    return;
  }
#pragma unroll
  for (int i = 0; i < 4; ++i) {
#pragma unroll
    for (int r = 0; r < 4; ++r) {
      const int row = row0 + wr + i * 16 + (lg << 2) + r;
#pragma unroll
      for (int j = 0; j < 4; ++j) {
        const int col = col0 + wc + j * 16 + lr;
        const float v = acc[i][j][r];
        if constexpr (FLAGOUT) {
          if (fl) ((float*)Cv)[(size_t)row * ldc + col] = v;
          else ((USHORT*)Cv)[(size_t)row * ldc + col] = f2bf(v);
        } else {
          ((USHORT*)Cv)[(size_t)row * ldc + col] = f2bf(v);
        }
      }
    }
  }
}

// ---------- ddk max over (h, m) per (b, l): atomicMax into mk[row] ----------
__global__ __launch_bounds__(256) void ddk_max_kernel(const float* __restrict__ qkf,
                                                      const USHORT* __restrict__ proj,
                                                      unsigned* __restrict__ mk) {
  __shared__ __align__(16) USHORT Ph[16384];
  __shared__ __align__(16) USHORT Ah[4096], Al[4096];
  const int t = threadIdx.x, lane = t & 63, wave = t >> 6;
  const int lr = lane & 15, lg = lane >> 4;
  const int bh = blockIdx.y, b = bh >> 4, h = bh & 15;
  const size_t grow0 = (size_t)b * 4096 + blockIdx.x * 64;
  {
#pragma unroll
    for (int c = 0; c < 8; ++c)
      *(uint4*)&Ph[t * 64 + ((c ^ (t & 7)) << 3)] = *(const uint4*)(proj + t * 64 + c * 8);
  }
  {
    const int r = t >> 2, kc = (t & 3) * 16;
    stage_hl16(qkf + (grow0 + r) * 2048 + 1024 + h * 64 + kc, Ah, Al, r, kc);
  }
  __syncthreads();
  f32x4 acc[16] = {};
#pragma unroll
  for (int ks = 0; ks < 2; ++ks) {
    const int koff = ks * 32 + (lg << 3);
    const int ar = wave * 16 + lr;
    short8 a_h = *(const short8*)&Ah[ar * 64 + (koff ^ ((ar & 7) << 3))];
    short8 a_l = *(const short8*)&Al[ar * 64 + (koff ^ ((ar & 7) << 3))];
#pragma unroll
    for (int n = 0; n < 16; ++n) {
      const int br = n * 16 + lr;
      short8 b_h = *(const short8*)&Ph[br * 64 + (koff ^ ((br & 7) << 3))];
      acc[n] = __builtin_amdgcn_mfma_f32_16x16x32_bf16(a_h, b_h, acc[n], 0, 0, 0);
      acc[n] = __builtin_amdgcn_mfma_f32_16x16x32_bf16(a_l, b_h, acc[n], 0, 0, 0);
    }
  }
#pragma unroll
  for (int r = 0; r < 4; ++r) {
    float m_ = acc[0][r];
#pragma unroll
    for (int n = 1; n < 16; ++n) m_ = fmaxf(m_, acc[n][r]);
    m_ = fmaxf(m_, __shfl_xor(m_, 1));
    m_ = fmaxf(m_, __shfl_xor(m_, 2));
    m_ = fmaxf(m_, __shfl_xor(m_, 4));
    m_ = fmaxf(m_, __shfl_xor(m_, 8));
    if (lr == 0) {
      const int row = (int)grow0 + wave * 16 + (lg << 2) + r;
      atomicMax(&mk[row], fkey(m_ * DNORM));
    }
  }
}

// ---------- kp = exp(ddk*DN - diag - mk) + EPS; kvs_ext += kp^T @ [v | 1] ----------
__global__ __launch_bounds__(256) void kvs_accum_kernel(const float* __restrict__ qkf,
                                                        const USHORT* __restrict__ vb,
                                                        const USHORT* __restrict__ proj,
                                                        const float* __restrict__ diag_k,
                                                        const unsigned* __restrict__ mk,
                                                        float* __restrict__ kvs_ext) {
  __shared__ __align__(16) USHORT Ph[8192];    // [128][64]
  __shared__ __align__(16) USHORT Ah[4096], Al[4096];
  __shared__ __align__(16) USHORT KpT[8192];   // [128][64]
  __shared__ __align__(16) USHORT Vt[5120];    // [80][64]
  const int t = threadIdx.x, lane = t & 63, wave = t >> 6;
  const int lr = lane & 15, lg = lane >> 4;
  const int bh = blockIdx.z, b = bh >> 4, h = bh & 15;
  const int fh = blockIdx.y;
  const int lstart = blockIdx.x * 512;
  {
    const int pr = t >> 1;
    const USHORT* src = proj + (size_t)(fh * 128 + pr) * 64;
#pragma unroll
    for (int c = 0; c < 4; ++c) {
      const int ch = (t & 1) * 4 + c;
      *(uint4*)&Ph[pr * 64 + ((ch ^ (pr & 7)) << 3)] = *(const uint4*)(src + ch * 8);
    }
  }
  if (t < 64) {
#pragma unroll
    for (int r = 64; r < 80; ++r) Vt[r * 64 + t] = (r == 64) ? (USHORT)0x3F80 : (USHORT)0;
  }
  f32x4 acc2[2][5] = {};
  for (int sub = 0; sub < 8; ++sub) {
    const int row0 = lstart + sub * 64;
    const size_t grow0 = (size_t)b * 4096 + row0;
    {
      const int r = t >> 2, kc = (t & 3) * 16;
      stage_hl16(qkf + (grow0 + r) * 2048 + 1024 + h * 64 + kc, Ah, Al, r, kc);
    }
    {
      const int rv = t & 63, dc = (t >> 6) * 16;
      const USHORT* sv = vb + (grow0 + rv) * 1024 + h * 64 + dc;
      uint4 u0 = *(const uint4*)sv;
      uint4 u1 = *(const uint4*)(sv + 8);
      unsigned wsrc[8] = {u0.x, u0.y, u0.z, u0.w, u1.x, u1.y, u1.z, u1.w};
#pragma unroll
      for (int i = 0; i < 8; ++i) {
        const int d0 = dc + 2 * i;
        Vt[d0 * 64 + (rv ^ ((d0 & 7) << 3))] = (USHORT)(wsrc[i] & 0xffff);
        Vt[(d0 + 1) * 64 + (rv ^ (((d0 + 1) & 7) << 3))] = (USHORT)(wsrc[i] >> 16);
      }
    }
    __syncthreads();
    f32x4 acc1[8] = {};
#pragma unroll
    for (int ks = 0; ks < 2; ++ks) {
      const int koff = ks * 32 + (lg << 3);
      const int ar = wave * 16 + lr;
      short8 a_h = *(const short8*)&Ah[ar * 64 + (koff ^ ((ar & 7) << 3))];
      short8 a_l = *(const short8*)&Al[ar * 64 + (koff ^ ((ar & 7) << 3))];
#pragma unroll
      for (int n = 0; n < 8; ++n) {
        const int br = n * 16 + lr;
        short8 b_h = *(const short8*)&Ph[br * 64 + (koff ^ ((br & 7) << 3))];
        acc1[n] = __builtin_amdgcn_mfma_f32_16x16x32_bf16(a_h, b_h, acc1[n], 0, 0, 0);
        acc1[n] = __builtin_amdgcn_mfma_f32_16x16x32_bf16(a_l, b_h, acc1[n], 0, 0, 0);
      }
    }
    const int rbase = wave * 16 + (lg << 2);
    float dg[4], mkr[4];
#pragma unroll
    for (int r = 0; r < 4; ++r) {
      dg[r] = diag_k[(grow0 + rbase + r) * 16 + h];
      mkr[r] = keyf(mk[grow0 + rbase + r]);
    }
#pragma unroll
    for (int n = 0; n < 8; ++n) {
      const int col = n * 16 + lr;
      USHORT pk[4];
#pragma unroll
      for (int r = 0; r < 4; ++r)
        pk[r] = f2bf(__expf(acc1[n][r] * DNORM - dg[r] - mkr[r]) + 1e-6f);
      const unsigned w0 = (unsigned)pk[0] | ((unsigned)pk[1] << 16);
      const unsigned w1 = (unsigned)pk[2] | ((unsigned)pk[3] << 16);
      *(uint2*)&KpT[col * 64 + (rbase ^ ((col & 7) << 3))] = make_uint2(w0, w1);
    }
    __syncthreads();
#pragma unroll
    for (int ks = 0; ks < 2; ++ks) {
      const int koff = ks * 32 + (lg << 3);
      short8 af[2];
#pragma unroll
      for (int i = 0; i < 2; ++i) {
        const int m = wave * 32 + i * 16 + lr;
        af[i] = *(const short8*)&KpT[m * 64 + (koff ^ ((m & 7) << 3))];
      }
#pragma unroll
      for (int c = 0; c < 5; ++c) {
        const int d = c * 16 + lr;
        short8 bv = *(const short8*)&Vt[d * 64 + (koff ^ ((d & 7) << 3))];
#pragma unroll
        for (int i = 0; i < 2; ++i)
          acc2[i][c] = __builtin_amdgcn_mfma_f32_16x16x32_bf16(af[i], bv, acc2[i][c], 0, 0, 0);
      }
    }
    __syncthreads();
  }
  float* basep = kvs_ext + (size_t)bh * 20480 + (size_t)fh * 128 * 80;
#pragma unroll
  for (int i = 0; i < 2; ++i) {
    const int mrow = wave * 32 + i * 16 + (lg << 2);
#pragma unroll
    for (int c = 0; c < 5; ++c) {
      const int col = c * 16 + lr;
      if (c == 4 && lr != 0) continue;
#pragma unroll
      for (int r = 0; r < 4; ++r)
        atomicAdd(basep + (size_t)(mrow + r) * 80 + col, acc2[i][c][r]);
    }
  }
}

// ---------- kvs fp32 [bh][m][d] -> bf16 transposed [bh][d][m] ----------
__global__ __launch_bounds__(256) void cvt_kvs_kernel(const float* __restrict__ kvs_ext,
                                                      USHORT* __restrict__ kvsT16) {
  const int bh = blockIdx.x;
  const float* src = kvs_ext + (size_t)bh * 20480;
  USHORT* dst = kvsT16 + (size_t)bh * 20480;
  const int m = threadIdx.x;
#pragma unroll 8
  for (int d = 0; d < 80; ++d)
    dst[d * 256 + m] = f2bf(src[m * 80 + d]);
}

// ---------- qp = exp(ddq*DN - diag - rowmax)+EPS; av = (qp@[kvs|ks])/den ----------
__global__ __launch_bounds__(256) void qav_kernel(const float* __restrict__ qkf,
                                                  const USHORT* __restrict__ proj,
                                                  const float* __restrict__ diag_q,
                                                  const USHORT* __restrict__ kvsT16,
                                                  USHORT* __restrict__ avb) {
  __shared__ __align__(16) USHORT smem[36864];
  USHORT* Ph = smem;            // [256][64] swz
  USHORT* Qp = smem;            // [64][256] swz (aliases Ph)
  USHORT* Ah = smem + 16384;    // [64][64]
  USHORT* Al = smem + 20480;    // [64][64]
  USHORT* Btl = smem + 16384;   // [80][256] swz (aliases Ah/Al)
  const int t = threadIdx.x, lane = t & 63, wave = t >> 6;
  const int lr = lane & 15, lg = lane >> 4;
  const int bh = blockIdx.y, b = bh >> 4, h = bh & 15;
  const size_t grow0 = (size_t)b * 4096 + blockIdx.x * 64;
  {
#pragma unroll
    for (int c = 0; c < 8; ++c)
      *(uint4*)&Ph[t * 64 + ((c ^ (t & 7)) << 3)] = *(const uint4*)(proj + t * 64 + c * 8);
  }
  {
    const int r = t >> 2, kc = (t & 3) * 16;
    stage_hl16(qkf + (grow0 + r) * 2048 + h * 64 + kc, Ah, Al, r, kc);
  }
  __syncthreads();
  f32x4 acc1[16] = {};
#pragma unroll
  for (int ks = 0; ks < 2; ++ks) {
    const int koff = ks * 32 + (lg << 3);
    const int ar = wave * 16 + lr;
    short8 a_h = *(const short8*)&Ah[ar * 64 + (koff ^ ((ar & 7) << 3))];
    short8 a_l = *(const short8*)&Al[ar * 64 + (koff ^ ((ar & 7) << 3))];
#pragma unroll
    for (int n = 0; n < 16; ++n) {
      const int br = n * 16 + lr;
      short8 b_h = *(const short8*)&Ph[br * 64 + (koff ^ ((br & 7) << 3))];
      acc1[n] = __builtin_amdgcn_mfma_f32_16x16x32_bf16(a_h, b_h, acc1[n], 0, 0, 0);
      acc1[n] = __builtin_amdgcn_mfma_f32_16x16x32_bf16(a_l, b_h, acc1[n], 0, 0, 0);
    }
  }
  __syncthreads();  // Ph/Ah/Al now dead; safe to overlay Qp/Btl
  {
    const USHORT* src = kvsT16 + (size_t)bh * 20480;
#pragma unroll
    for (int c = 0; c < 10; ++c) {
      const int e = c * 256 + t;        // 8-short chunk id, 0..2559
      const int d = e >> 5, ch = e & 31;
      *(uint4*)&Btl[d * 256 + ((ch ^ (d & 7)) << 3)] = *(const uint4*)(src + d * 256 + ch * 8);
    }
  }
  const int rbase = wave * 16 + (lg << 2);
  float dg[4], mx[4];
#pragma unroll
  for (int r = 0; r < 4; ++r) dg[r] = diag_q[(grow0 + rbase + r) * 16 + h];
#pragma unroll
  for (int r = 0; r < 4; ++r) {
    float m_ = acc1[0][r];
#pragma unroll
    for (int n = 1; n < 16; ++n) m_ = fmaxf(m_, acc1[n][r]);
    m_ = fmaxf(m_, __shfl_xor(m_, 1));
    m_ = fmaxf(m_, __shfl_xor(m_, 2));
    m_ = fmaxf(m_, __shfl_xor(m_, 4));
    m_ = fmaxf(m_, __shfl_xor(m_, 8));
    mx[r] = m_ * DNORM;
  }
#pragma unroll
  for (int n = 0; n < 16; ++n) {
    const int col = n * 16 + lr;
#pragma unroll
    for (int r = 0; r < 4; ++r) {
      const int row = rbase + r;
      Qp[row * 256 + (col ^ ((row & 7) << 3))] =
          f2bf(__expf(acc1[n][r] * DNORM - dg[r] - mx[r]) + 1e-6f);
    }
  }
  __syncthreads();
  f32x4 acc2[5] = {};
#pragma unroll
  for (int ks2 = 0; ks2 < 8; ++ks2) {
    const int koff = ks2 * 32 + (lg << 3);
    const int ar = wave * 16 + lr;
    short8 a = *(const short8*)&Qp[ar * 256 + (koff ^ ((ar & 7) << 3))];
#pragma unroll
    for (int c = 0; c < 5; ++c) {
      const int cr = c * 16 + lr;
      short8 bv = *(const short8*)&Btl[cr * 256 + (koff ^ ((cr & 7) << 3))];
      acc2[c] = __builtin_amdgcn_mfma_f32_16x16x32_bf16(a, bv, acc2[c], 0, 0, 0);
    }
  }
#pragma unroll
  for (int r = 0; r < 4; ++r) {
    const float den = __shfl(acc2[4][r], (lane & 48));
#pragma unroll
    for (int c = 0; c < 4; ++c) {
      const float o = acc2[c][r] / den;
      avb[(grow0 + rbase + r) * 1024 + h * 64 + c * 16 + lr] = f2bf(o);
    }
  }
}

// ---------- launch ----------
extern "C" void kernel_launch(void* const* d_in, const int* in_sizes, int n_in,
                              void* d_out, int out_size, void* d_ws, size_t ws_size,
                              hipStream_t stream) {
  char* ws = (char*)d_ws;

  const size_t OFF_FLAG = 0;                       // 256
  const size_t OFF_WQKVT = 256;                    // 6,291,456
  const size_t OFF_WOT = OFF_WQKVT + 6291456;      // 2,097,152
  const size_t OFF_PROJC = OFF_WOT + 2097152;      // 32,768
  const size_t OFF_SINUC = OFF_PROJC + 32768;      // 524,288
  const size_t OFF_XH = OFF_SINUC + 524288;        // 16,777,216 (reused as av)
  const size_t OFF_XL = OFF_XH + 16777216;         // 16,777,216 (unused)
  const size_t OFF_QKF = OFF_XL + 16777216;        // 67,108,864 (8192x2048 fp32 rotated q,k)
  const size_t OFF_VB = OFF_QKF + 67108864;        // 16,777,216 (8192x1024 bf16 v)
  const size_t OFF_DIAGQ = OFF_VB + 16777216;      // 524,288
  const size_t OFF_DIAGK = OFF_DIAGQ + 524288;     // 524,288
  const size_t OFF_MK = OFF_DIAGK + 524288;        // 32,768
  const size_t OFF_KVS = OFF_MK + 32768;           // 2,621,440
  const size_t OFF_KVST = OFF_KVS + 2621440;       // 1,310,720

  int* flag = (int*)(ws + OFF_FLAG);
  USHORT* wqkvt = (USHORT*)(ws + OFF_WQKVT);
  USHORT* wot = (USHORT*)(ws + OFF_WOT);
  USHORT* projc = (USHORT*)(ws + OFF_PROJC);
  USHORT* sinuc = (USHORT*)(ws + OFF_SINUC);
  USHORT* xh = (USHORT*)(ws + OFF_XH);
  USHORT* avb = (USHORT*)(ws + OFF_XH);  // alias: xh dead after gemm1
  float* qkf = (float*)(ws + OFF_QKF);
  USHORT* vb = (USHORT*)(ws + OFF_VB);
  float* diagq = (float*)(ws + OFF_DIAGQ);
  float* diagk = (float*)(ws + OFF_DIAGK);
  unsigned* mk = (unsigned*)(ws + OFF_MK);
  float* kvsb = (float*)(ws + OFF_KVS);
  USHORT* kvst = (USHORT*)(ws + OFF_KVST);

  hipMemsetAsync(ws + OFF_FLAG, 0, 256, stream);
  hipMemsetAsync(ws + OFF_MK, 0, 32768, stream);
  hipMemsetAsync(ws + OFF_KVS, 0, 2621440, stream);

  detect_kernel<<<1, 256, 0, stream>>>((const USHORT*)d_in[1], flag);
  cvt_x_kernel<<<4368, 256, 0, stream>>>(d_in[0], xh, d_in[5], d_in[6], projc, sinuc, flag);
  transpose_w_kernel<<<dim3(16, 16, 4), 256, 0, stream>>>(d_in[1], d_in[2], d_in[3], d_in[4],
                                                          wqkvt, wot, flag);
  // qkv = x @ [Wq|Wk|Wv]; rotary fused, q/k stored fp32, v stored bf16
  gemm_bt<true, false><<<dim3(24, 64), 256, 0, stream>>>(
      xh, wqkvt, qkf, vb, sinuc, diagq, diagk,
      8192, 3072, 1024, 1024, 1024, 2048, 1024, 2048, flag);
  ddk_max_kernel<<<dim3(64, 32), 256, 0, stream>>>(qkf, projc, mk);
  kvs_accum_kernel<<<dim3(8, 2, 32), 256, 0, stream>>>(qkf, vb, projc, diagk, mk, kvsb);
  cvt_kvs_kernel<<<32, 256, 0, stream>>>(kvsb, kvst);
  qav_kernel<<<dim3(64, 32), 256, 0, stream>>>(qkf, projc, diagq, kvst, avb);
  // out = av @ Wo  (output dtype per flag)
  gemm_bt<false, true><<<dim3(8, 64), 256, 0, stream>>>(
      avb, wot, d_out, nullptr, nullptr, nullptr, nullptr,
      8192, 1024, 1024, 1024, 1024, 1024, 0, 0, flag);
}